// Round 13
// baseline (1213.598 us; speedup 1.0000x reference)
//
#include <hip/hip_runtime.h>
#include <hip/hip_fp16.h>

#define NUM_GRAPHS 8192
#define BSHIFT 12
#define BSIZE 4096     // nodes per bucket
#define CHUNK 4096     // edges per chunk
#define NTHR 256

// DIAGNOSTIC ROUND: kernels repeat their (idempotent) work REPS_* times so
// per-dispatch durations exceed the harness poison-fill rows (~312us) and
// become visible in rocprof top-5 with their counters. Revert next round.
#define REPS_COUNT 4
#define REPS_SCAT  8
#define REPS_NODE  4
#define REPS_HIST  4
#define REPS_AGG   4

// ===== K1a: per-chunk bucket counts -> countsT[chunk*256 + b] (coalesced) ===
__global__ void __launch_bounds__(NTHR)
count_kernel(const int* __restrict__ dst, int E, int nchunks,
             unsigned* __restrict__ countsT) {
    __shared__ unsigned cnt[256];
    int tid = threadIdx.x;
    int E4 = E >> 2;
    const int4* d4 = (const int4*)dst;
    for (int rep = 0; rep < REPS_COUNT; ++rep)
    for (int chunk = blockIdx.x; chunk < nchunks; chunk += gridDim.x) {
        cnt[tid] = 0; __syncthreads();
        int b4 = chunk * (CHUNK / 4);
        #pragma unroll
        for (int k = 0; k < 4; ++k) {
            int idx = b4 + k * NTHR + tid;
            if (idx < E4) {
                int4 v = d4[idx];
                atomicAdd(&cnt[v.x >> BSHIFT], 1u);
                atomicAdd(&cnt[v.y >> BSHIFT], 1u);
                atomicAdd(&cnt[v.z >> BSHIFT], 1u);
                atomicAdd(&cnt[v.w >> BSHIFT], 1u);
            }
        }
        if (chunk == nchunks - 1 && tid < (E & 3))
            atomicAdd(&cnt[dst[E4 * 4 + tid] >> BSHIFT], 1u);
        __syncthreads();
        countsT[(size_t)chunk * 256 + tid] = cnt[tid];
        __syncthreads();
    }
}

// ===== K1b: per-bucket exclusive scan over chunks (1 wave/bucket) ===========
__global__ void __launch_bounds__(64)
chunkscan_kernel(const unsigned* __restrict__ countsT, int nchunks,
                 unsigned* __restrict__ base2T, unsigned* __restrict__ total) {
    int b = blockIdx.x, lane = threadIdx.x;
    unsigned run = 0;
    for (int c0 = 0; c0 < nchunks; c0 += 64) {
        int c = c0 + lane;
        unsigned v = (c < nchunks) ? countsT[(size_t)c * 256 + b] : 0u;
        unsigned s = v;
        #pragma unroll
        for (int off = 1; off < 64; off <<= 1) {
            unsigned o = __shfl_up(s, off);
            if (lane >= off) s += o;
        }
        if (c < nchunks) base2T[(size_t)c * 256 + b] = run + s - v;
        run += __shfl(s, 63);
    }
    if (lane == 0) total[b] = run;
}

// ===== K1b2: scan totals -> gbase[0..256] ===================================
__global__ void gbase_kernel(const unsigned* __restrict__ total,
                             unsigned* __restrict__ gbase) {
    __shared__ unsigned s[256];
    int tid = threadIdx.x;
    unsigned v = total[tid];
    s[tid] = v; __syncthreads();
    #pragma unroll
    for (int off = 1; off < 256; off <<= 1) {
        unsigned a = (tid >= off) ? s[tid - off] : 0u;
        __syncthreads();
        s[tid] += a;
        __syncthreads();
    }
    gbase[tid] = s[tid] - v;
    if (tid == 255) gbase[256] = s[255];
}

// ===== K1c: scatter (dst_lo<<20|src) into exact slab positions ==============
__global__ void __launch_bounds__(NTHR)
scatter_kernel(const int* __restrict__ src, const int* __restrict__ dst,
               int E, int nchunks,
               const unsigned* __restrict__ base2T,
               const unsigned* __restrict__ gbase,
               unsigned* __restrict__ slab) {
    __shared__ unsigned cnt[256];
    __shared__ unsigned lbase[256];
    __shared__ unsigned sbase[256];
    __shared__ unsigned staged[CHUNK + 4];
    __shared__ unsigned char sbuck[CHUNK + 4];
    __shared__ unsigned s_tot;

    const int4* s4 = (const int4*)src;
    const int4* d4 = (const int4*)dst;
    const int E4 = E >> 2;
    const int tid = threadIdx.x;

    for (int rep = 0; rep < REPS_SCAT; ++rep)
    for (int chunk = blockIdx.x; chunk < nchunks; chunk += gridDim.x) {
        cnt[tid] = 0; __syncthreads();
        int b4 = chunk * (CHUNK / 4);
        int4 vd[4], vs[4];
        unsigned short r[16];
        #pragma unroll
        for (int k = 0; k < 4; ++k) {
            int idx = b4 + k * NTHR + tid;
            if (idx < E4) { vd[k] = d4[idx]; vs[k] = s4[idx]; }
            else          { vd[k] = make_int4(-1, -1, -1, -1); }
        }
        #pragma unroll
        for (int k = 0; k < 4; ++k) {
            if (vd[k].x >= 0) {
                r[4*k+0] = (unsigned short)atomicAdd(&cnt[vd[k].x >> BSHIFT], 1u);
                r[4*k+1] = (unsigned short)atomicAdd(&cnt[vd[k].y >> BSHIFT], 1u);
                r[4*k+2] = (unsigned short)atomicAdd(&cnt[vd[k].z >> BSHIFT], 1u);
                r[4*k+3] = (unsigned short)atomicAdd(&cnt[vd[k].w >> BSHIFT], 1u);
            }
        }
        int tr = -1, tsrc = 0, tdlo = 0, tb = 0;
        if (chunk == nchunks - 1 && tid < (E & 3)) {
            int i = E4 * 4 + tid;
            int d = dst[i];
            tb = d >> BSHIFT;
            tr = (int)atomicAdd(&cnt[tb], 1u);
            tdlo = d & (BSIZE - 1);
            tsrc = src[i];
        }
        __syncthreads();
        sbase[tid] = gbase[tid] + base2T[(size_t)chunk * 256 + tid];
        if (tid < 64) {
            unsigned run = 0;
            for (int c0 = 0; c0 < 256; c0 += 64) {
                unsigned v = cnt[c0 + tid];
                unsigned s = v;
                #pragma unroll
                for (int off = 1; off < 64; off <<= 1) {
                    unsigned o = __shfl_up(s, off);
                    if (tid >= off) s += o;
                }
                lbase[c0 + tid] = run + s - v;
                run += __shfl(s, 63);
            }
            if (tid == 0) s_tot = run;
        }
        __syncthreads();

        #pragma unroll
        for (int k = 0; k < 4; ++k) {
            if (vd[k].x >= 0) {
                int d0 = vd[k].x, d1 = vd[k].y, d2 = vd[k].z, d3 = vd[k].w;
                unsigned b0 = (unsigned)d0 >> BSHIFT, b1 = (unsigned)d1 >> BSHIFT;
                unsigned b2 = (unsigned)d2 >> BSHIFT, b3 = (unsigned)d3 >> BSHIFT;
                unsigned p0 = lbase[b0] + r[4*k+0];
                unsigned p1 = lbase[b1] + r[4*k+1];
                unsigned p2 = lbase[b2] + r[4*k+2];
                unsigned p3 = lbase[b3] + r[4*k+3];
                staged[p0] = ((unsigned)(d0 & (BSIZE-1)) << 20) | (unsigned)vs[k].x;
                staged[p1] = ((unsigned)(d1 & (BSIZE-1)) << 20) | (unsigned)vs[k].y;
                staged[p2] = ((unsigned)(d2 & (BSIZE-1)) << 20) | (unsigned)vs[k].z;
                staged[p3] = ((unsigned)(d3 & (BSIZE-1)) << 20) | (unsigned)vs[k].w;
                sbuck[p0] = (unsigned char)b0;
                sbuck[p1] = (unsigned char)b1;
                sbuck[p2] = (unsigned char)b2;
                sbuck[p3] = (unsigned char)b3;
            }
        }
        if (tr >= 0) {
            unsigned p = lbase[tb] + (unsigned)tr;
            staged[p] = ((unsigned)tdlo << 20) | (unsigned)tsrc;
            sbuck[p] = (unsigned char)tb;
        }
        __syncthreads();

        unsigned tot = s_tot;
        for (unsigned pos = tid; pos < tot; pos += NTHR) {
            unsigned b = sbuck[pos];
            slab[sbase[b] + (pos - lbase[b])] = staged[pos];
        }
        __syncthreads();
    }
}

// ===== K2: h = x @ W (persistent, grid-stride) ==============================
__global__ void node_h_kernel(const float* __restrict__ x,
                              const float* __restrict__ W,
                              float* __restrict__ h, int N) {
    int gwave = (blockIdx.x * blockDim.x + threadIdx.x) >> 6;
    int lane = threadIdx.x & 63;
    int half = lane >> 5;
    int l32  = lane & 31;
    int total_waves = (gridDim.x * blockDim.x) >> 6;
    float4 wv = ((const float4*)W)[l32];
    for (int rep = 0; rep < REPS_NODE; ++rep)
    for (int node = gwave * 2 + half; node < N; node += total_waves * 2) {
        float4 xv = ((const float4*)(x + (size_t)node * 128))[l32];
        float v = xv.x * wv.x + xv.y * wv.y + xv.z * wv.z + xv.w * wv.w;
        #pragma unroll
        for (int d = 16; d >= 1; d >>= 1) v += __shfl_xor(v, d);
        if (l32 == 0) h[node] = v;
    }
}

// ===== K3: per-bucket degree hist (contiguous range) -> hsh/pkw =============
__global__ void __launch_bounds__(1024)
hist_finalize_kernel(const unsigned* __restrict__ slab,
                     const unsigned* __restrict__ gbase,
                     const float* __restrict__ h, const int* __restrict__ batch,
                     unsigned short* __restrict__ hsh, unsigned* __restrict__ pkw,
                     int N) {
    __shared__ unsigned hist[BSIZE];
    int b = blockIdx.x, tid = threadIdx.x;
    for (int rep = 0; rep < REPS_HIST; ++rep) {
        for (int t = tid; t < BSIZE; t += 1024) hist[t] = 0;
        __syncthreads();
        unsigned s0 = gbase[b], s1 = gbase[b + 1];
        for (unsigned i = s0 + tid; i < s1; i += 1024)
            atomicAdd(&hist[slab[i] >> 20], 1u);
        __syncthreads();
        int base = b << BSHIFT;
        int lim = N - base; if (lim > BSIZE) lim = BSIZE;
        for (int t = tid; t < lim; t += 1024) {
            float di = rsqrtf((float)(hist[t] + 1u));   // +1 self-loop
            hsh[base + t] = __half_as_ushort(__float2half(di * h[base + t]));
            pkw[base + t] = ((unsigned)batch[base + t] << 16) |
                            __half_as_ushort(__float2half(di));
        }
        __syncthreads();
    }
}

// ===== K4: per-bucket aggregation (contiguous range) -> pooled ==============
__global__ void __launch_bounds__(1024)
aggregate_kernel(const unsigned* __restrict__ slab,
                 const unsigned* __restrict__ gbase,
                 const unsigned* __restrict__ pkw,
                 const unsigned short* __restrict__ hsh,
                 float* __restrict__ pooled, float* __restrict__ pooled_dummy,
                 int N) {
    __shared__ float pool[NUM_GRAPHS];
    __shared__ unsigned pkw_s[BSIZE];
    int b = blockIdx.x, tid = threadIdx.x;
    int base = b << BSHIFT;
    int lim = N - base; if (lim > BSIZE) lim = BSIZE;

    for (int rep = 0; rep < REPS_AGG; ++rep) {
        float* tgt = (rep == REPS_AGG - 1) ? pooled : pooled_dummy;
        for (int t = tid; t < NUM_GRAPHS; t += 1024) pool[t] = 0.0f;
        for (int t = tid; t < BSIZE; t += 1024)
            pkw_s[t] = (t < lim) ? pkw[base + t] : 0u;
        __syncthreads();

        for (int t = tid; t < lim; t += 1024) {
            unsigned w = pkw_s[t];
            float di = __half2float(__ushort_as_half((unsigned short)(w & 0xFFFFu)));
            float c = di * __half2float(__ushort_as_half(hsh[base + t]));
            atomicAdd(&pool[w >> 16], c);
        }
        unsigned s0 = gbase[b], s1 = gbase[b + 1];
        for (unsigned i = s0 + tid; i < s1; i += 1024) {
            unsigned e = slab[i];
            unsigned w = pkw_s[e >> 20];
            float hv = __half2float(__ushort_as_half(hsh[e & 0xFFFFFu]));
            float di = __half2float(__ushort_as_half((unsigned short)(w & 0xFFFFu)));
            atomicAdd(&pool[w >> 16], hv * di);
        }
        __syncthreads();
        int g_lo = (int)(pkw_s[0] >> 16);
        int g_hi = (lim > 0) ? (int)(pkw_s[lim - 1] >> 16) : g_lo;
        for (int g = g_lo + tid; g <= g_hi; g += 1024) atomicAdd(&tgt[g], pool[g]);
        __syncthreads();
    }
}

// ===== K5: affine ==========================================================
__global__ void out_kernel(const float* __restrict__ pooled,
                           const float* __restrict__ pp_w,
                           const float* __restrict__ pp_b,
                           float* __restrict__ out) {
    int g = blockIdx.x * blockDim.x + threadIdx.x;
    if (g < NUM_GRAPHS) out[g] = pooled[g] * pp_w[0] + pp_b[0];
}

// ===== Fallback path (tiny ws / oversized N): correctness only =============
__global__ void deg_atomic_kernel(const int* __restrict__ dst, int E,
                                  unsigned* __restrict__ deg) {
    int tid = blockIdx.x * blockDim.x + threadIdx.x;
    int stride = gridDim.x * blockDim.x;
    for (int i = tid; i < E; i += stride) atomicAdd(&deg[dst[i]], 1u);
}

__global__ void node_fb_kernel(const float* __restrict__ x,
                               const float* __restrict__ W,
                               const unsigned* __restrict__ deg,
                               const int* __restrict__ batch,
                               unsigned short* __restrict__ hsh,
                               unsigned* __restrict__ pkw, int N) {
    int gtid = blockIdx.x * blockDim.x + threadIdx.x;
    int wave = gtid >> 6;
    int lane = threadIdx.x & 63;
    int half = lane >> 5;
    int l32  = lane & 31;
    int node = wave * 2 + half;
    if (node >= N) return;
    float4 xv = ((const float4*)(x + (size_t)node * 128))[l32];
    float4 wv = ((const float4*)W)[l32];
    float v = xv.x * wv.x + xv.y * wv.y + xv.z * wv.z + xv.w * wv.w;
    #pragma unroll
    for (int d = 16; d >= 1; d >>= 1) v += __shfl_xor(v, d);
    if (l32 == 0) {
        float di = rsqrtf((float)(deg[node] + 1u));
        hsh[node] = __half_as_ushort(__float2half(di * v));
        pkw[node] = ((unsigned)batch[node] << 16) | __half_as_ushort(__float2half(di));
    }
}

__global__ void pool_self_fb_kernel(const unsigned short* __restrict__ hsh,
                                    const unsigned* __restrict__ pkw,
                                    float* __restrict__ pooled, int N) {
    int i = blockIdx.x * blockDim.x + threadIdx.x;
    if (i >= N) return;
    unsigned w = pkw[i];
    float di = __half2float(__ushort_as_half((unsigned short)(w & 0xFFFFu)));
    atomicAdd(&pooled[w >> 16], di * __half2float(__ushort_as_half(hsh[i])));
}

__global__ void __launch_bounds__(512)
edge_direct_kernel(const int* __restrict__ src, const int* __restrict__ dst, int E,
                   const unsigned short* __restrict__ hsh,
                   const unsigned* __restrict__ pkw,
                   float* __restrict__ pooled) {
    __shared__ float pool[NUM_GRAPHS];
    for (int g = threadIdx.x; g < NUM_GRAPHS; g += 512) pool[g] = 0.0f;
    __syncthreads();
    int tid = blockIdx.x * 512 + threadIdx.x;
    int stride = gridDim.x * 512;
    for (int i = tid; i < E; i += stride) {
        unsigned w = pkw[dst[i]];
        float c = __half2float(__ushort_as_half(hsh[src[i]])) *
                  __half2float(__ushort_as_half((unsigned short)(w & 0xFFFFu)));
        atomicAdd(&pool[w >> 16], c);
    }
    __syncthreads();
    for (int g = threadIdx.x; g < NUM_GRAPHS; g += 512)
        if (pool[g] != 0.0f) atomicAdd(&pooled[g], pool[g]);
}

extern "C" void kernel_launch(void* const* d_in, const int* in_sizes, int n_in,
                              void* d_out, int out_size, void* d_ws, size_t ws_size,
                              hipStream_t stream) {
    const float* x    = (const float*)d_in[0];
    const float* W    = (const float*)d_in[1];
    const float* pp_w = (const float*)d_in[2];
    const float* pp_b = (const float*)d_in[3];
    const int*   ei   = (const int*)d_in[4];
    const int*   batch= (const int*)d_in[5];
    float* out = (float*)d_out;

    const int E = in_sizes[4] / 2;
    const int N = in_sizes[5];
    const int* src = ei;
    const int* dst = ei + E;
    int NBUK = (N + BSIZE - 1) >> BSHIFT;
    int nchunks = (E + CHUNK - 1) / CHUNK;

    char* ws = (char*)d_ws;
    size_t off = 0;
    auto alloc = [&](size_t bytes) {
        size_t o = off; off = (off + bytes + 255) & ~(size_t)255; return o;
    };
    size_t pooled_off = alloc((size_t)NUM_GRAPHS * 4);      // memset 0
    size_t dummy_off  = alloc((size_t)NUM_GRAPHS * 4);      // diagnostic sink
    size_t h_off      = alloc((size_t)N * 4);               // h / deg (fallback)
    size_t hsh_off    = alloc((size_t)N * 2);
    size_t pkw_off    = alloc((size_t)N * 4);
    size_t counts_off = alloc((size_t)nchunks * 256 * 4);
    size_t base2_off  = alloc((size_t)nchunks * 256 * 4);
    size_t total_off  = alloc(256 * 4);
    size_t gbase_off  = alloc(257 * 4);
    size_t slab_off   = alloc((size_t)E * 4);

    bool fast_ok = (NBUK <= 256) && (N <= (1 << 20)) && (off <= ws_size);

    float*          pooled = (float*)(ws + pooled_off);
    float*          pdummy = (float*)(ws + dummy_off);
    float*          h      = (float*)(ws + h_off);
    unsigned*       deg    = (unsigned*)(ws + h_off);       // fallback alias
    unsigned short* hsh    = (unsigned short*)(ws + hsh_off);
    unsigned*       pkw    = (unsigned*)(ws + pkw_off);
    unsigned*       countsT= (unsigned*)(ws + counts_off);
    unsigned*       base2T = (unsigned*)(ws + base2_off);
    unsigned*       total  = (unsigned*)(ws + total_off);
    unsigned*       gbase  = (unsigned*)(ws + gbase_off);
    unsigned*       slab   = (unsigned*)(ws + slab_off);

    hipMemsetAsync(pooled, 0, (size_t)NUM_GRAPHS * 4, stream);

    if (fast_ok) {
        int grid_c = nchunks < 2048 ? nchunks : 2048;
        count_kernel<<<grid_c, NTHR, 0, stream>>>(dst, E, nchunks, countsT);
        chunkscan_kernel<<<256, 64, 0, stream>>>(countsT, nchunks, base2T, total);
        gbase_kernel<<<1, 256, 0, stream>>>(total, gbase);
        scatter_kernel<<<grid_c, NTHR, 0, stream>>>(src, dst, E, nchunks,
                                                    base2T, gbase, slab);
        node_h_kernel<<<8192, 256, 0, stream>>>(x, W, h, N);
        hist_finalize_kernel<<<NBUK, 1024, 0, stream>>>(slab, gbase, h, batch,
                                                        hsh, pkw, N);
        aggregate_kernel<<<NBUK, 1024, 0, stream>>>(slab, gbase, pkw, hsh,
                                                    pooled, pdummy, N);
    } else {
        hipMemsetAsync(deg, 0, (size_t)N * 4, stream);
        deg_atomic_kernel<<<2048, 256, 0, stream>>>(dst, E, deg);
        int node_blocks = (N + 7) / 8;
        node_fb_kernel<<<node_blocks, 256, 0, stream>>>(x, W, deg, batch, hsh, pkw, N);
        pool_self_fb_kernel<<<(N + 255) / 256, 256, 0, stream>>>(hsh, pkw, pooled, N);
        edge_direct_kernel<<<512, 512, 0, stream>>>(src, dst, E, hsh, pkw, pooled);
    }

    out_kernel<<<(NUM_GRAPHS + 255) / 256, 256, 0, stream>>>(pooled, pp_w, pp_b, out);
}

// Round 14
// 344.824 us; speedup vs baseline: 3.5195x; 3.5195x over previous
//
#include <hip/hip_runtime.h>
#include <hip/hip_fp16.h>

#define NUM_GRAPHS 8192
#define BSHIFT 12
#define BSIZE 4096     // nodes per bucket
#define CHUNK 4096     // edges per chunk
#define NTHR 256
#define REPL 16        // aggregate window replicas
#define WINDOW 128     // max graphs spanned per bucket (fallback if exceeded)
#define WPAD 129       // padded stride (bank spread)

// ===== K1a: per-chunk bucket counts -> countsT[chunk*256 + b] ===============
__global__ void __launch_bounds__(NTHR)
count_kernel(const int* __restrict__ dst, int E, int nchunks,
             unsigned* __restrict__ countsT) {
    __shared__ unsigned cnt[256];
    int tid = threadIdx.x;
    int E4 = E >> 2;
    const int4* d4 = (const int4*)dst;
    for (int chunk = blockIdx.x; chunk < nchunks; chunk += gridDim.x) {
        cnt[tid] = 0; __syncthreads();
        int b4 = chunk * (CHUNK / 4);
        #pragma unroll
        for (int k = 0; k < 4; ++k) {
            int idx = b4 + k * NTHR + tid;
            if (idx < E4) {
                int4 v = d4[idx];
                atomicAdd(&cnt[v.x >> BSHIFT], 1u);
                atomicAdd(&cnt[v.y >> BSHIFT], 1u);
                atomicAdd(&cnt[v.z >> BSHIFT], 1u);
                atomicAdd(&cnt[v.w >> BSHIFT], 1u);
            }
        }
        if (chunk == nchunks - 1 && tid < (E & 3))
            atomicAdd(&cnt[dst[E4 * 4 + tid] >> BSHIFT], 1u);
        __syncthreads();
        countsT[(size_t)chunk * 256 + tid] = cnt[tid];
        __syncthreads();
    }
}

// ===== K1b: per-bucket exclusive scan over chunks (1 wave/bucket) ===========
__global__ void __launch_bounds__(64)
chunkscan_kernel(const unsigned* __restrict__ countsT, int nchunks,
                 unsigned* __restrict__ base2T, unsigned* __restrict__ total) {
    int b = blockIdx.x, lane = threadIdx.x;
    unsigned run = 0;
    for (int c0 = 0; c0 < nchunks; c0 += 64) {
        int c = c0 + lane;
        unsigned v = (c < nchunks) ? countsT[(size_t)c * 256 + b] : 0u;
        unsigned s = v;
        #pragma unroll
        for (int off = 1; off < 64; off <<= 1) {
            unsigned o = __shfl_up(s, off);
            if (lane >= off) s += o;
        }
        if (c < nchunks) base2T[(size_t)c * 256 + b] = run + s - v;
        run += __shfl(s, 63);
    }
    if (lane == 0) total[b] = run;
}

// ===== K1b2: scan totals -> gbase[0..256] ===================================
__global__ void gbase_kernel(const unsigned* __restrict__ total,
                             unsigned* __restrict__ gbase) {
    __shared__ unsigned s[256];
    int tid = threadIdx.x;
    unsigned v = total[tid];
    s[tid] = v; __syncthreads();
    #pragma unroll
    for (int off = 1; off < 256; off <<= 1) {
        unsigned a = (tid >= off) ? s[tid - off] : 0u;
        __syncthreads();
        s[tid] += a;
        __syncthreads();
    }
    gbase[tid] = s[tid] - v;
    if (tid == 255) gbase[256] = s[255];
}

// ===== K1c: scatter (dst_lo<<20|src) into exact slab positions ==============
__global__ void __launch_bounds__(NTHR)
scatter_kernel(const int* __restrict__ src, const int* __restrict__ dst,
               int E, int nchunks,
               const unsigned* __restrict__ base2T,
               const unsigned* __restrict__ gbase,
               unsigned* __restrict__ slab) {
    __shared__ unsigned cnt[256];
    __shared__ unsigned lbase[256];
    __shared__ unsigned sbase[256];
    __shared__ unsigned staged[CHUNK + 4];
    __shared__ unsigned char sbuck[CHUNK + 4];
    __shared__ unsigned s_tot;

    const int4* s4 = (const int4*)src;
    const int4* d4 = (const int4*)dst;
    const int E4 = E >> 2;
    const int tid = threadIdx.x;

    for (int chunk = blockIdx.x; chunk < nchunks; chunk += gridDim.x) {
        cnt[tid] = 0; __syncthreads();
        int b4 = chunk * (CHUNK / 4);
        int4 vd[4], vs[4];
        unsigned short r[16];
        #pragma unroll
        for (int k = 0; k < 4; ++k) {
            int idx = b4 + k * NTHR + tid;
            if (idx < E4) { vd[k] = d4[idx]; vs[k] = s4[idx]; }
            else          { vd[k] = make_int4(-1, -1, -1, -1); }
        }
        #pragma unroll
        for (int k = 0; k < 4; ++k) {
            if (vd[k].x >= 0) {
                r[4*k+0] = (unsigned short)atomicAdd(&cnt[vd[k].x >> BSHIFT], 1u);
                r[4*k+1] = (unsigned short)atomicAdd(&cnt[vd[k].y >> BSHIFT], 1u);
                r[4*k+2] = (unsigned short)atomicAdd(&cnt[vd[k].z >> BSHIFT], 1u);
                r[4*k+3] = (unsigned short)atomicAdd(&cnt[vd[k].w >> BSHIFT], 1u);
            }
        }
        int tr = -1, tsrc = 0, tdlo = 0, tb = 0;
        if (chunk == nchunks - 1 && tid < (E & 3)) {
            int i = E4 * 4 + tid;
            int d = dst[i];
            tb = d >> BSHIFT;
            tr = (int)atomicAdd(&cnt[tb], 1u);
            tdlo = d & (BSIZE - 1);
            tsrc = src[i];
        }
        __syncthreads();
        sbase[tid] = gbase[tid] + base2T[(size_t)chunk * 256 + tid];
        if (tid < 64) {
            unsigned run = 0;
            for (int c0 = 0; c0 < 256; c0 += 64) {
                unsigned v = cnt[c0 + tid];
                unsigned s = v;
                #pragma unroll
                for (int off = 1; off < 64; off <<= 1) {
                    unsigned o = __shfl_up(s, off);
                    if (tid >= off) s += o;
                }
                lbase[c0 + tid] = run + s - v;
                run += __shfl(s, 63);
            }
            if (tid == 0) s_tot = run;
        }
        __syncthreads();

        #pragma unroll
        for (int k = 0; k < 4; ++k) {
            if (vd[k].x >= 0) {
                int d0 = vd[k].x, d1 = vd[k].y, d2 = vd[k].z, d3 = vd[k].w;
                unsigned b0 = (unsigned)d0 >> BSHIFT, b1 = (unsigned)d1 >> BSHIFT;
                unsigned b2 = (unsigned)d2 >> BSHIFT, b3 = (unsigned)d3 >> BSHIFT;
                unsigned p0 = lbase[b0] + r[4*k+0];
                unsigned p1 = lbase[b1] + r[4*k+1];
                unsigned p2 = lbase[b2] + r[4*k+2];
                unsigned p3 = lbase[b3] + r[4*k+3];
                staged[p0] = ((unsigned)(d0 & (BSIZE-1)) << 20) | (unsigned)vs[k].x;
                staged[p1] = ((unsigned)(d1 & (BSIZE-1)) << 20) | (unsigned)vs[k].y;
                staged[p2] = ((unsigned)(d2 & (BSIZE-1)) << 20) | (unsigned)vs[k].z;
                staged[p3] = ((unsigned)(d3 & (BSIZE-1)) << 20) | (unsigned)vs[k].w;
                sbuck[p0] = (unsigned char)b0;
                sbuck[p1] = (unsigned char)b1;
                sbuck[p2] = (unsigned char)b2;
                sbuck[p3] = (unsigned char)b3;
            }
        }
        if (tr >= 0) {
            unsigned p = lbase[tb] + (unsigned)tr;
            staged[p] = ((unsigned)tdlo << 20) | (unsigned)tsrc;
            sbuck[p] = (unsigned char)tb;
        }
        __syncthreads();

        unsigned tot = s_tot;
        for (unsigned pos = tid; pos < tot; pos += NTHR) {
            unsigned b = sbuck[pos];
            slab[sbase[b] + (pos - lbase[b])] = staged[pos];
        }
        __syncthreads();
    }
}

// ===== K2: per-bucket degree hist, 2 half-range blocks -> deg0/deg1 =========
__global__ void __launch_bounds__(1024)
hist_kernel(const unsigned* __restrict__ slab,
            const unsigned* __restrict__ gbase,
            unsigned* __restrict__ deg0, unsigned* __restrict__ deg1, int N) {
    __shared__ unsigned hist[BSIZE];
    int bp = blockIdx.x, tid = threadIdx.x;
    int b = bp >> 1, half = bp & 1;
    for (int t = tid; t < BSIZE; t += 1024) hist[t] = 0;
    __syncthreads();
    unsigned s0 = gbase[b], s1 = gbase[b + 1];
    unsigned len = s1 - s0, hl = len >> 1;
    unsigned r0 = s0 + (half ? hl : 0);
    unsigned r1 = half ? s1 : (s0 + hl);
    for (unsigned i = r0 + tid; i < r1; i += 1024)
        atomicAdd(&hist[slab[i] >> 20], 1u);
    __syncthreads();
    int base = b << BSHIFT;
    int lim = N - base; if (lim > BSIZE) lim = BSIZE;
    unsigned* degP = half ? deg1 : deg0;
    for (int t = tid; t < lim; t += 1024) degP[base + t] = hist[t];
}

// ===== K3: node: h=x@W fused with finalize (dinv -> hsh, pkw) ===============
__global__ void node_kernel(const float* __restrict__ x,
                            const float* __restrict__ W,
                            const unsigned* __restrict__ deg0,
                            const unsigned* __restrict__ deg1,
                            const int* __restrict__ batch,
                            unsigned short* __restrict__ hsh,
                            unsigned* __restrict__ pkw, int N) {
    int gwave = (blockIdx.x * blockDim.x + threadIdx.x) >> 6;
    int lane = threadIdx.x & 63;
    int half = lane >> 5;
    int l32  = lane & 31;
    int total_waves = (gridDim.x * blockDim.x) >> 6;
    float4 wv = ((const float4*)W)[l32];
    for (int node = gwave * 2 + half; node < N; node += total_waves * 2) {
        float4 xv = ((const float4*)(x + (size_t)node * 128))[l32];
        float v = xv.x * wv.x + xv.y * wv.y + xv.z * wv.z + xv.w * wv.w;
        #pragma unroll
        for (int d = 16; d >= 1; d >>= 1) v += __shfl_xor(v, d);
        if (l32 == 0) {
            float di = rsqrtf((float)(deg0[node] + deg1[node] + 1u));
            hsh[node] = __half_as_ushort(__float2half(di * v));
            pkw[node] = ((unsigned)batch[node] << 16) |
                        __half_as_ushort(__float2half(di));
        }
    }
}

// ===== K4: aggregate, 2 half-range blocks, replicated graph-window ==========
__global__ void __launch_bounds__(1024)
aggregate_kernel(const unsigned* __restrict__ slab,
                 const unsigned* __restrict__ gbase,
                 const unsigned* __restrict__ pkw,
                 const unsigned short* __restrict__ hsh,
                 float* __restrict__ pooled, int N) {
    __shared__ unsigned pkw_s[BSIZE];                 // 16 KB
    __shared__ union {
        float win[REPL * WPAD];                       // 8.25 KB
        float pool[NUM_GRAPHS];                       // 32 KB (fallback)
    } u;
    int bp = blockIdx.x, tid = threadIdx.x;
    int b = bp >> 1, half = bp & 1;
    int base = b << BSHIFT;
    int lim = N - base; if (lim > BSIZE) lim = BSIZE;

    for (int t = tid; t < BSIZE; t += 1024) pkw_s[t] = (t < lim) ? pkw[base + t] : 0u;
    __syncthreads();
    int g_lo = (int)(pkw_s[0] >> 16);
    int g_hi = (lim > 0) ? (int)(pkw_s[lim - 1] >> 16) : g_lo;
    int width = g_hi - g_lo + 1;

    unsigned s0 = gbase[b], s1 = gbase[b + 1];
    unsigned len = s1 - s0, hl = len >> 1;
    unsigned r0 = s0 + (half ? hl : 0);
    unsigned r1 = half ? s1 : (s0 + hl);
    int n0 = half * (BSIZE / 2);
    int n1 = (half + 1) * (BSIZE / 2); if (n1 > lim) n1 = lim;

    if (width <= WINDOW) {
        for (int t = tid; t < REPL * WPAD; t += 1024) u.win[t] = 0.0f;
        __syncthreads();
        int r = tid & (REPL - 1);
        // self-loop terms (this half's node range)
        for (int t = n0 + tid; t < n1; t += 1024) {
            unsigned w = pkw_s[t];
            float di = __half2float(__ushort_as_half((unsigned short)(w & 0xFFFFu)));
            float c = di * __half2float(__ushort_as_half(hsh[base + t]));
            atomicAdd(&u.win[r * WPAD + ((w >> 16) - g_lo)], c);
        }
        // edge terms (this half's slab range)
        for (unsigned i = r0 + tid; i < r1; i += 1024) {
            unsigned e = slab[i];
            unsigned w = pkw_s[e >> 20];
            float hv = __half2float(__ushort_as_half(hsh[e & 0xFFFFFu]));
            float di = __half2float(__ushort_as_half((unsigned short)(w & 0xFFFFu)));
            atomicAdd(&u.win[r * WPAD + ((w >> 16) - g_lo)], hv * di);
        }
        __syncthreads();
        for (int g = tid; g < width; g += 1024) {
            float s = 0.0f;
            #pragma unroll
            for (int rr = 0; rr < REPL; ++rr) s += u.win[rr * WPAD + g];
            atomicAdd(&pooled[g_lo + g], s);
        }
    } else {
        // fallback: full pool (rare — bucket spans >WINDOW graphs)
        for (int t = tid; t < NUM_GRAPHS; t += 1024) u.pool[t] = 0.0f;
        __syncthreads();
        for (int t = n0 + tid; t < n1; t += 1024) {
            unsigned w = pkw_s[t];
            float di = __half2float(__ushort_as_half((unsigned short)(w & 0xFFFFu)));
            float c = di * __half2float(__ushort_as_half(hsh[base + t]));
            atomicAdd(&u.pool[w >> 16], c);
        }
        for (unsigned i = r0 + tid; i < r1; i += 1024) {
            unsigned e = slab[i];
            unsigned w = pkw_s[e >> 20];
            float hv = __half2float(__ushort_as_half(hsh[e & 0xFFFFFu]));
            float di = __half2float(__ushort_as_half((unsigned short)(w & 0xFFFFu)));
            atomicAdd(&u.pool[w >> 16], hv * di);
        }
        __syncthreads();
        for (int g = g_lo + tid; g <= g_hi; g += 1024)
            atomicAdd(&pooled[g], u.pool[g]);
    }
}

// ===== K5: affine ==========================================================
__global__ void out_kernel(const float* __restrict__ pooled,
                           const float* __restrict__ pp_w,
                           const float* __restrict__ pp_b,
                           float* __restrict__ out) {
    int g = blockIdx.x * blockDim.x + threadIdx.x;
    if (g < NUM_GRAPHS) out[g] = pooled[g] * pp_w[0] + pp_b[0];
}

// ===== Fallback path (tiny ws / oversized N): correctness only =============
__global__ void deg_atomic_kernel(const int* __restrict__ dst, int E,
                                  unsigned* __restrict__ deg) {
    int tid = blockIdx.x * blockDim.x + threadIdx.x;
    int stride = gridDim.x * blockDim.x;
    for (int i = tid; i < E; i += stride) atomicAdd(&deg[dst[i]], 1u);
}

__global__ void node_fb_kernel(const float* __restrict__ x,
                               const float* __restrict__ W,
                               const unsigned* __restrict__ deg,
                               const int* __restrict__ batch,
                               unsigned short* __restrict__ hsh,
                               unsigned* __restrict__ pkw, int N) {
    int gtid = blockIdx.x * blockDim.x + threadIdx.x;
    int wave = gtid >> 6;
    int lane = threadIdx.x & 63;
    int half = lane >> 5;
    int l32  = lane & 31;
    int node = wave * 2 + half;
    if (node >= N) return;
    float4 xv = ((const float4*)(x + (size_t)node * 128))[l32];
    float4 wv = ((const float4*)W)[l32];
    float v = xv.x * wv.x + xv.y * wv.y + xv.z * wv.z + xv.w * wv.w;
    #pragma unroll
    for (int d = 16; d >= 1; d >>= 1) v += __shfl_xor(v, d);
    if (l32 == 0) {
        float di = rsqrtf((float)(deg[node] + 1u));
        hsh[node] = __half_as_ushort(__float2half(di * v));
        pkw[node] = ((unsigned)batch[node] << 16) | __half_as_ushort(__float2half(di));
    }
}

__global__ void pool_self_fb_kernel(const unsigned short* __restrict__ hsh,
                                    const unsigned* __restrict__ pkw,
                                    float* __restrict__ pooled, int N) {
    int i = blockIdx.x * blockDim.x + threadIdx.x;
    if (i >= N) return;
    unsigned w = pkw[i];
    float di = __half2float(__ushort_as_half((unsigned short)(w & 0xFFFFu)));
    atomicAdd(&pooled[w >> 16], di * __half2float(__ushort_as_half(hsh[i])));
}

__global__ void __launch_bounds__(512)
edge_direct_kernel(const int* __restrict__ src, const int* __restrict__ dst, int E,
                   const unsigned short* __restrict__ hsh,
                   const unsigned* __restrict__ pkw,
                   float* __restrict__ pooled) {
    __shared__ float pool[NUM_GRAPHS];
    for (int g = threadIdx.x; g < NUM_GRAPHS; g += 512) pool[g] = 0.0f;
    __syncthreads();
    int tid = blockIdx.x * 512 + threadIdx.x;
    int stride = gridDim.x * 512;
    for (int i = tid; i < E; i += stride) {
        unsigned w = pkw[dst[i]];
        float c = __half2float(__ushort_as_half(hsh[src[i]])) *
                  __half2float(__ushort_as_half((unsigned short)(w & 0xFFFFu)));
        atomicAdd(&pool[w >> 16], c);
    }
    __syncthreads();
    for (int g = threadIdx.x; g < NUM_GRAPHS; g += 512)
        if (pool[g] != 0.0f) atomicAdd(&pooled[g], pool[g]);
}

extern "C" void kernel_launch(void* const* d_in, const int* in_sizes, int n_in,
                              void* d_out, int out_size, void* d_ws, size_t ws_size,
                              hipStream_t stream) {
    const float* x    = (const float*)d_in[0];
    const float* W    = (const float*)d_in[1];
    const float* pp_w = (const float*)d_in[2];
    const float* pp_b = (const float*)d_in[3];
    const int*   ei   = (const int*)d_in[4];
    const int*   batch= (const int*)d_in[5];
    float* out = (float*)d_out;

    const int E = in_sizes[4] / 2;
    const int N = in_sizes[5];
    const int* src = ei;
    const int* dst = ei + E;
    int NBUK = (N + BSIZE - 1) >> BSHIFT;
    int nchunks = (E + CHUNK - 1) / CHUNK;

    char* ws = (char*)d_ws;
    size_t off = 0;
    auto alloc = [&](size_t bytes) {
        size_t o = off; off = (off + bytes + 255) & ~(size_t)255; return o;
    };
    size_t pooled_off = alloc((size_t)NUM_GRAPHS * 4);      // memset 0
    size_t deg0_off   = alloc((size_t)N * 4);               // also fallback deg
    size_t deg1_off   = alloc((size_t)N * 4);
    size_t hsh_off    = alloc((size_t)N * 2);
    size_t pkw_off    = alloc((size_t)N * 4);
    size_t counts_off = alloc((size_t)nchunks * 256 * 4);
    size_t base2_off  = alloc((size_t)nchunks * 256 * 4);
    size_t total_off  = alloc(256 * 4);
    size_t gbase_off  = alloc(257 * 4);
    size_t slab_off   = alloc((size_t)E * 4);

    bool fast_ok = (NBUK <= 256) && (N <= (1 << 20)) && (off <= ws_size);

    float*          pooled = (float*)(ws + pooled_off);
    unsigned*       deg0   = (unsigned*)(ws + deg0_off);
    unsigned*       deg1   = (unsigned*)(ws + deg1_off);
    unsigned short* hsh    = (unsigned short*)(ws + hsh_off);
    unsigned*       pkw    = (unsigned*)(ws + pkw_off);
    unsigned*       countsT= (unsigned*)(ws + counts_off);
    unsigned*       base2T = (unsigned*)(ws + base2_off);
    unsigned*       total  = (unsigned*)(ws + total_off);
    unsigned*       gbase  = (unsigned*)(ws + gbase_off);
    unsigned*       slab   = (unsigned*)(ws + slab_off);

    hipMemsetAsync(pooled, 0, (size_t)NUM_GRAPHS * 4, stream);

    if (fast_ok) {
        int grid_c = nchunks < 2048 ? nchunks : 2048;
        count_kernel<<<grid_c, NTHR, 0, stream>>>(dst, E, nchunks, countsT);
        chunkscan_kernel<<<256, 64, 0, stream>>>(countsT, nchunks, base2T, total);
        gbase_kernel<<<1, 256, 0, stream>>>(total, gbase);
        scatter_kernel<<<grid_c, NTHR, 0, stream>>>(src, dst, E, nchunks,
                                                    base2T, gbase, slab);
        hist_kernel<<<2 * NBUK, 1024, 0, stream>>>(slab, gbase, deg0, deg1, N);
        node_kernel<<<8192, 256, 0, stream>>>(x, W, deg0, deg1, batch, hsh, pkw, N);
        aggregate_kernel<<<2 * NBUK, 1024, 0, stream>>>(slab, gbase, pkw, hsh,
                                                        pooled, N);
    } else {
        hipMemsetAsync(deg0, 0, (size_t)N * 4, stream);
        deg_atomic_kernel<<<2048, 256, 0, stream>>>(dst, E, deg0);
        int node_blocks = (N + 7) / 8;
        node_fb_kernel<<<node_blocks, 256, 0, stream>>>(x, W, deg0, batch, hsh, pkw, N);
        pool_self_fb_kernel<<<(N + 255) / 256, 256, 0, stream>>>(hsh, pkw, pooled, N);
        edge_direct_kernel<<<512, 512, 0, stream>>>(src, dst, E, hsh, pkw, pooled);
    }

    out_kernel<<<(NUM_GRAPHS + 255) / 256, 256, 0, stream>>>(pooled, pp_w, pp_b, out);
}

// Round 15
// 292.541 us; speedup vs baseline: 4.1485x; 1.1787x over previous
//
#include <hip/hip_runtime.h>
#include <hip/hip_fp16.h>

#define NUM_GRAPHS 8192
#define BSHIFT 12
#define BSIZE 4096     // nodes per bucket
#define CHUNK 4096     // edges per chunk
#define NGRP 32        // cursor/slab groups
#define REPL 8         // aggregate window replicas
#define WINDOW 256     // max graphs spanned per bucket (fallback: direct atomics)
#define WPAD 257       // padded replica stride

// ===== K1: scatter (dst_lo<<20|src) into per-(group,bucket) sub-slabs =======
// R9-proven: group-private cursors, LDS-staged bucket-sorted flush.
__global__ void __launch_bounds__(256)
pair_scatter_kernel(const int* __restrict__ src, const int* __restrict__ dst,
                    int E, int nchunks, int NBUK, int capG,
                    unsigned* __restrict__ cursor, unsigned* __restrict__ slab) {
    __shared__ unsigned cnt[256];
    __shared__ unsigned lbase[256];
    __shared__ unsigned sbase[256];
    __shared__ unsigned staged[CHUNK];
    __shared__ unsigned char sbuck[CHUNK];
    __shared__ unsigned s_tot;

    const int4* s4 = (const int4*)src;
    const int4* d4 = (const int4*)dst;
    int E4 = E >> 2;
    int tid = threadIdx.x;
    int g = blockIdx.x & (NGRP - 1);

    for (int chunk = blockIdx.x; chunk < nchunks; chunk += gridDim.x) {
        cnt[tid] = 0; __syncthreads();
        int b4 = chunk * (CHUNK / 4);
        int4 vd[4], vs[4];
        unsigned short r[16];
        #pragma unroll
        for (int k = 0; k < 4; ++k) {
            int idx = b4 + k * 256 + tid;
            if (idx < E4) { vd[k] = d4[idx]; vs[k] = s4[idx]; }
            else          { vd[k] = make_int4(-1, -1, -1, -1); }
        }
        #pragma unroll
        for (int k = 0; k < 4; ++k) {
            if (vd[k].x >= 0) {
                r[4*k+0] = (unsigned short)atomicAdd(&cnt[vd[k].x >> BSHIFT], 1u);
                r[4*k+1] = (unsigned short)atomicAdd(&cnt[vd[k].y >> BSHIFT], 1u);
                r[4*k+2] = (unsigned short)atomicAdd(&cnt[vd[k].z >> BSHIFT], 1u);
                r[4*k+3] = (unsigned short)atomicAdd(&cnt[vd[k].w >> BSHIFT], 1u);
            }
        }
        __syncthreads();
        lbase[tid] = cnt[tid]; __syncthreads();
        #pragma unroll
        for (int off = 1; off < 256; off <<= 1) {
            unsigned a = (tid >= off) ? lbase[tid - off] : 0u;
            __syncthreads();
            lbase[tid] += a;
            __syncthreads();
        }
        if (tid == 255) s_tot = lbase[255];
        if (tid < NBUK && cnt[tid])
            sbase[tid] = atomicAdd(&cursor[g * 256 + tid], cnt[tid]);
        unsigned excl = lbase[tid] - cnt[tid];
        __syncthreads();
        lbase[tid] = excl;
        __syncthreads();

        #pragma unroll
        for (int k = 0; k < 4; ++k) {
            if (vd[k].x >= 0) {
                int d0 = vd[k].x, d1 = vd[k].y, d2 = vd[k].z, d3 = vd[k].w;
                unsigned b0 = (unsigned)d0 >> BSHIFT, b1 = (unsigned)d1 >> BSHIFT;
                unsigned b2 = (unsigned)d2 >> BSHIFT, b3 = (unsigned)d3 >> BSHIFT;
                unsigned p0 = lbase[b0] + r[4*k+0];
                unsigned p1 = lbase[b1] + r[4*k+1];
                unsigned p2 = lbase[b2] + r[4*k+2];
                unsigned p3 = lbase[b3] + r[4*k+3];
                staged[p0] = ((unsigned)(d0 & (BSIZE-1)) << 20) | (unsigned)vs[k].x;
                staged[p1] = ((unsigned)(d1 & (BSIZE-1)) << 20) | (unsigned)vs[k].y;
                staged[p2] = ((unsigned)(d2 & (BSIZE-1)) << 20) | (unsigned)vs[k].z;
                staged[p3] = ((unsigned)(d3 & (BSIZE-1)) << 20) | (unsigned)vs[k].w;
                sbuck[p0] = (unsigned char)b0;
                sbuck[p1] = (unsigned char)b1;
                sbuck[p2] = (unsigned char)b2;
                sbuck[p3] = (unsigned char)b3;
            }
        }
        __syncthreads();
        unsigned tot = s_tot;
        for (unsigned pos = tid; pos < tot; pos += 256) {
            unsigned b = sbuck[pos];
            unsigned gp = sbase[b] + (pos - lbase[b]);
            if (gp < (unsigned)capG)
                slab[((size_t)g * NBUK + b) * capG + gp] = staged[pos];
        }
        __syncthreads();
    }
    if (blockIdx.x == 0 && tid < (E & 3)) {
        int i = (E & ~3) + tid;
        int d = dst[i];
        unsigned b = (unsigned)d >> BSHIFT;
        unsigned p = atomicAdd(&cursor[b], 1u);
        if (p < (unsigned)capG)
            slab[(size_t)b * capG + p] =
                ((unsigned)(d & (BSIZE-1)) << 20) | (unsigned)src[i];
    }
}

// ===== K2: degree hist — 8 segments concurrently (MLP), 2 half-blocks ======
__global__ void __launch_bounds__(512)
hist_kernel(const unsigned* __restrict__ slab, int capG,
            const unsigned* __restrict__ cursor,
            unsigned* __restrict__ deg0, unsigned* __restrict__ deg1,
            int N, int NBUK) {
    __shared__ unsigned hist[BSIZE];
    int bp = blockIdx.x, tid = threadIdx.x;
    int b = bp >> 1, half = bp & 1;
    for (int t = tid; t < BSIZE; t += 512) hist[t] = 0;
    __syncthreads();

    int g0 = half * 16;
    for (int gg = g0; gg < g0 + 16; gg += 8) {
        unsigned n[8], maxn = 0;
        const unsigned* sp[8];
        #pragma unroll
        for (int k = 0; k < 8; ++k) {
            unsigned nn = cursor[(gg + k) * 256 + b];
            if (nn > (unsigned)capG) nn = capG;
            n[k] = nn; if (nn > maxn) maxn = nn;
            sp[k] = slab + ((size_t)(gg + k) * NBUK + b) * capG;
        }
        for (unsigned i = tid; i < maxn; i += 512) {
            unsigned e[8];
            #pragma unroll
            for (int k = 0; k < 8; ++k) e[k] = (i < n[k]) ? sp[k][i] : 0xFFFFFFFFu;
            #pragma unroll
            for (int k = 0; k < 8; ++k)
                if (e[k] != 0xFFFFFFFFu) atomicAdd(&hist[e[k] >> 20], 1u);
        }
    }
    __syncthreads();
    int base = b << BSHIFT;
    int lim = N - base; if (lim > BSIZE) lim = BSIZE;
    unsigned* degP = half ? deg1 : deg0;
    for (int t = tid; t < lim; t += 512) degP[base + t] = hist[t];
}

// ===== K3: node: h=x@W fused with finalize (dinv -> hsh, pkw) ===============
__global__ void node_kernel(const float* __restrict__ x,
                            const float* __restrict__ W,
                            const unsigned* __restrict__ deg0,
                            const unsigned* __restrict__ deg1,
                            const int* __restrict__ batch,
                            unsigned short* __restrict__ hsh,
                            unsigned* __restrict__ pkw, int N) {
    int gwave = (blockIdx.x * blockDim.x + threadIdx.x) >> 6;
    int lane = threadIdx.x & 63;
    int half = lane >> 5;
    int l32  = lane & 31;
    int total_waves = (gridDim.x * blockDim.x) >> 6;
    float4 wv = ((const float4*)W)[l32];
    for (int node = gwave * 2 + half; node < N; node += total_waves * 2) {
        float4 xv = ((const float4*)(x + (size_t)node * 128))[l32];
        float v = xv.x * wv.x + xv.y * wv.y + xv.z * wv.z + xv.w * wv.w;
        #pragma unroll
        for (int d = 16; d >= 1; d >>= 1) v += __shfl_xor(v, d);
        if (l32 == 0) {
            float di = rsqrtf((float)(deg0[node] + deg1[node] + 1u));
            hsh[node] = __half_as_ushort(__float2half(di * v));
            pkw[node] = ((unsigned)batch[node] << 16) |
                        __half_as_ushort(__float2half(di));
        }
    }
}

// ===== K4: aggregate — 4 quarter-blocks/bucket, 8-segment MLP, window pool ==
__global__ void __launch_bounds__(512)
aggregate_kernel(const unsigned* __restrict__ slab, int capG,
                 const unsigned* __restrict__ cursor,
                 const unsigned* __restrict__ pkw,
                 const unsigned short* __restrict__ hsh,
                 float* __restrict__ pooled, int N, int NBUK) {
    __shared__ unsigned pkw_s[BSIZE];        // 16 KB
    __shared__ float win[REPL * WPAD];       // 8.2 KB
    int bp = blockIdx.x, tid = threadIdx.x;
    int b = bp >> 2, q = bp & 3;
    int base = b << BSHIFT;
    int lim = N - base; if (lim > BSIZE) lim = BSIZE;

    for (int t = tid; t < BSIZE; t += 512) pkw_s[t] = (t < lim) ? pkw[base + t] : 0u;
    for (int t = tid; t < REPL * WPAD; t += 512) win[t] = 0.0f;
    __syncthreads();
    int g_lo = (int)(pkw_s[0] >> 16);
    int g_hi = (lim > 0) ? (int)(pkw_s[lim - 1] >> 16) : g_lo;
    int width = g_hi - g_lo + 1;
    bool windowed = (width <= WINDOW);
    int r = tid & (REPL - 1);

    // self-loop terms: this quarter's node range
    int n0 = q * (BSIZE / 4);
    int n1 = (q + 1) * (BSIZE / 4); if (n1 > lim) n1 = lim;
    for (int t = n0 + tid; t < n1; t += 512) {
        unsigned w = pkw_s[t];
        float di = __half2float(__ushort_as_half((unsigned short)(w & 0xFFFFu)));
        float c = di * __half2float(__ushort_as_half(hsh[base + t]));
        if (windowed) atomicAdd(&win[r * WPAD + ((w >> 16) - g_lo)], c);
        else          atomicAdd(&pooled[w >> 16], c);
    }

    // edge terms: this quarter's 8 segments processed CONCURRENTLY (8x MLP)
    int g0 = q * 8;
    unsigned n[8], maxn = 0;
    const unsigned* sp[8];
    #pragma unroll
    for (int k = 0; k < 8; ++k) {
        unsigned nn = cursor[(g0 + k) * 256 + b];
        if (nn > (unsigned)capG) nn = capG;
        n[k] = nn; if (nn > maxn) maxn = nn;
        sp[k] = slab + ((size_t)(g0 + k) * NBUK + b) * capG;
    }
    for (unsigned i = tid; i < maxn; i += 512) {
        unsigned e[8]; bool v[8];
        #pragma unroll
        for (int k = 0; k < 8; ++k) { v[k] = (i < n[k]); e[k] = v[k] ? sp[k][i] : 0u; }
        unsigned w[8];
        #pragma unroll
        for (int k = 0; k < 8; ++k) w[k] = pkw_s[e[k] >> 20];
        unsigned short hb[8];
        #pragma unroll
        for (int k = 0; k < 8; ++k) hb[k] = hsh[e[k] & 0xFFFFFu];
        #pragma unroll
        for (int k = 0; k < 8; ++k) {
            float hv = __half2float(__ushort_as_half(hb[k]));
            float di = __half2float(__ushort_as_half((unsigned short)(w[k] & 0xFFFFu)));
            float c = v[k] ? hv * di : 0.0f;
            if (windowed) atomicAdd(&win[r * WPAD + ((w[k] >> 16) - g_lo)], c);
            else if (v[k]) atomicAdd(&pooled[w[k] >> 16], c);
        }
    }
    __syncthreads();
    if (windowed) {
        for (int g = tid; g < width; g += 512) {
            float s = 0.0f;
            #pragma unroll
            for (int rr = 0; rr < REPL; ++rr) s += win[rr * WPAD + g];
            atomicAdd(&pooled[g_lo + g], s);
        }
    }
}

// ===== K5: affine ==========================================================
__global__ void out_kernel(const float* __restrict__ pooled,
                           const float* __restrict__ pp_w,
                           const float* __restrict__ pp_b,
                           float* __restrict__ out) {
    int g = blockIdx.x * blockDim.x + threadIdx.x;
    if (g < NUM_GRAPHS) out[g] = pooled[g] * pp_w[0] + pp_b[0];
}

// ===== Fallback path (tiny ws / oversized N): correctness only =============
__global__ void deg_atomic_kernel(const int* __restrict__ dst, int E,
                                  unsigned* __restrict__ deg) {
    int tid = blockIdx.x * blockDim.x + threadIdx.x;
    int stride = gridDim.x * blockDim.x;
    for (int i = tid; i < E; i += stride) atomicAdd(&deg[dst[i]], 1u);
}

__global__ void node_fb_kernel(const float* __restrict__ x,
                               const float* __restrict__ W,
                               const unsigned* __restrict__ deg,
                               const int* __restrict__ batch,
                               unsigned short* __restrict__ hsh,
                               unsigned* __restrict__ pkw, int N) {
    int gtid = blockIdx.x * blockDim.x + threadIdx.x;
    int wave = gtid >> 6;
    int lane = threadIdx.x & 63;
    int half = lane >> 5;
    int l32  = lane & 31;
    int node = wave * 2 + half;
    if (node >= N) return;
    float4 xv = ((const float4*)(x + (size_t)node * 128))[l32];
    float4 wv = ((const float4*)W)[l32];
    float v = xv.x * wv.x + xv.y * wv.y + xv.z * wv.z + xv.w * wv.w;
    #pragma unroll
    for (int d = 16; d >= 1; d >>= 1) v += __shfl_xor(v, d);
    if (l32 == 0) {
        float di = rsqrtf((float)(deg[node] + 1u));
        hsh[node] = __half_as_ushort(__float2half(di * v));
        pkw[node] = ((unsigned)batch[node] << 16) | __half_as_ushort(__float2half(di));
    }
}

__global__ void pool_self_fb_kernel(const unsigned short* __restrict__ hsh,
                                    const unsigned* __restrict__ pkw,
                                    float* __restrict__ pooled, int N) {
    int i = blockIdx.x * blockDim.x + threadIdx.x;
    if (i >= N) return;
    unsigned w = pkw[i];
    float di = __half2float(__ushort_as_half((unsigned short)(w & 0xFFFFu)));
    atomicAdd(&pooled[w >> 16], di * __half2float(__ushort_as_half(hsh[i])));
}

__global__ void __launch_bounds__(512)
edge_direct_kernel(const int* __restrict__ src, const int* __restrict__ dst, int E,
                   const unsigned short* __restrict__ hsh,
                   const unsigned* __restrict__ pkw,
                   float* __restrict__ pooled) {
    __shared__ float pool[NUM_GRAPHS];
    for (int g = threadIdx.x; g < NUM_GRAPHS; g += 512) pool[g] = 0.0f;
    __syncthreads();
    int tid = blockIdx.x * 512 + threadIdx.x;
    int stride = gridDim.x * 512;
    for (int i = tid; i < E; i += stride) {
        unsigned w = pkw[dst[i]];
        float c = __half2float(__ushort_as_half(hsh[src[i]])) *
                  __half2float(__ushort_as_half((unsigned short)(w & 0xFFFFu)));
        atomicAdd(&pool[w >> 16], c);
    }
    __syncthreads();
    for (int g = threadIdx.x; g < NUM_GRAPHS; g += 512)
        if (pool[g] != 0.0f) atomicAdd(&pooled[g], pool[g]);
}

extern "C" void kernel_launch(void* const* d_in, const int* in_sizes, int n_in,
                              void* d_out, int out_size, void* d_ws, size_t ws_size,
                              hipStream_t stream) {
    const float* x    = (const float*)d_in[0];
    const float* W    = (const float*)d_in[1];
    const float* pp_w = (const float*)d_in[2];
    const float* pp_b = (const float*)d_in[3];
    const int*   ei   = (const int*)d_in[4];
    const int*   batch= (const int*)d_in[5];
    float* out = (float*)d_out;

    const int E = in_sizes[4] / 2;
    const int N = in_sizes[5];
    const int* src = ei;
    const int* dst = ei + E;
    int NBUK = (N + BSIZE - 1) >> BSHIFT;
    int nchunks = (E + CHUNK - 1) / CHUNK;

    char* ws = (char*)d_ws;
    size_t off = 0;
    auto alloc = [&](size_t bytes) {
        size_t o = off; off = (off + bytes + 255) & ~(size_t)255; return o;
    };
    // zero region: pooled | cursor  (single memset)
    size_t zero_bytes = (size_t)NUM_GRAPHS * 4 + (size_t)NGRP * 256 * 4;
    size_t zero_off   = alloc(zero_bytes);
    float*    pooled = (float*)(ws + zero_off);
    unsigned* cursor = (unsigned*)(ws + zero_off + (size_t)NUM_GRAPHS * 4);

    size_t deg0_off = alloc((size_t)N * 4);      // also fallback deg
    size_t deg1_off = alloc((size_t)N * 4);
    size_t hsh_off  = alloc((size_t)N * 2);
    size_t pkw_off  = alloc((size_t)N * 4);

    int meanG = E / (NBUK * NGRP) + 1;
    int capG = (meanG + meanG / 8 + 512 + 3) & ~3;   // ~17 sigma, 16B-aligned
    size_t slab_off = alloc((size_t)NGRP * NBUK * (size_t)capG * 4);

    bool fast_ok = (NBUK <= 256) && (N <= (1 << 20)) && (off <= ws_size);

    unsigned*       deg0 = (unsigned*)(ws + deg0_off);
    unsigned*       deg1 = (unsigned*)(ws + deg1_off);
    unsigned short* hsh  = (unsigned short*)(ws + hsh_off);
    unsigned*       pkw  = (unsigned*)(ws + pkw_off);
    unsigned*       slab = (unsigned*)(ws + slab_off);

    hipMemsetAsync(ws + zero_off, 0, zero_bytes, stream);

    if (fast_ok) {
        int grid = nchunks < 4096 ? nchunks : 4096;
        pair_scatter_kernel<<<grid, 256, 0, stream>>>(src, dst, E, nchunks, NBUK,
                                                      capG, cursor, slab);
        hist_kernel<<<2 * NBUK, 512, 0, stream>>>(slab, capG, cursor,
                                                  deg0, deg1, N, NBUK);
        node_kernel<<<8192, 256, 0, stream>>>(x, W, deg0, deg1, batch, hsh, pkw, N);
        aggregate_kernel<<<4 * NBUK, 512, 0, stream>>>(slab, capG, cursor, pkw,
                                                       hsh, pooled, N, NBUK);
    } else {
        hipMemsetAsync(deg0, 0, (size_t)N * 4, stream);
        deg_atomic_kernel<<<2048, 256, 0, stream>>>(dst, E, deg0);
        int node_blocks = (N + 7) / 8;
        node_fb_kernel<<<node_blocks, 256, 0, stream>>>(x, W, deg0, batch, hsh, pkw, N);
        pool_self_fb_kernel<<<(N + 255) / 256, 256, 0, stream>>>(hsh, pkw, pooled, N);
        edge_direct_kernel<<<512, 512, 0, stream>>>(src, dst, E, hsh, pkw, pooled);
    }

    out_kernel<<<(NUM_GRAPHS + 255) / 256, 256, 0, stream>>>(pooled, pp_w, pp_b, out);
}

// Round 16
// 276.243 us; speedup vs baseline: 4.3932x; 1.0590x over previous
//
#include <hip/hip_runtime.h>
#include <hip/hip_fp16.h>

#define NUM_GRAPHS 8192
#define BSHIFT 12
#define BSIZE 4096     // nodes per bucket
#define CHUNK 4096     // edges per chunk
#define NGRP 32        // cursor/slab groups
#define REPL 8         // aggregate window replicas
#define WINDOW 256     // max graphs spanned per bucket
#define WPAD 257       // padded replica stride
#define FNT 512        // fused kernel block size

// ===== K1: scatter (dst_lo<<20|src) into per-(group,bucket) sub-slabs =======
// Group-private cursors (R9) + wave0 shuffle-scan lbase (R12): ~8 barriers.
__global__ void __launch_bounds__(256)
pair_scatter_kernel(const int* __restrict__ src, const int* __restrict__ dst,
                    int E, int nchunks, int NBUK, int capG,
                    unsigned* __restrict__ cursor, unsigned* __restrict__ slab) {
    __shared__ unsigned cnt[256];
    __shared__ unsigned lbase[256];
    __shared__ unsigned sbase[256];
    __shared__ unsigned staged[CHUNK];
    __shared__ unsigned char sbuck[CHUNK];
    __shared__ unsigned s_tot;

    const int4* s4 = (const int4*)src;
    const int4* d4 = (const int4*)dst;
    int E4 = E >> 2;
    int tid = threadIdx.x;
    int g = blockIdx.x & (NGRP - 1);

    for (int chunk = blockIdx.x; chunk < nchunks; chunk += gridDim.x) {
        cnt[tid] = 0; __syncthreads();
        int b4 = chunk * (CHUNK / 4);
        int4 vd[4], vs[4];
        unsigned short r[16];
        #pragma unroll
        for (int k = 0; k < 4; ++k) {
            int idx = b4 + k * 256 + tid;
            if (idx < E4) { vd[k] = d4[idx]; vs[k] = s4[idx]; }
            else          { vd[k] = make_int4(-1, -1, -1, -1); }
        }
        #pragma unroll
        for (int k = 0; k < 4; ++k) {
            if (vd[k].x >= 0) {
                r[4*k+0] = (unsigned short)atomicAdd(&cnt[vd[k].x >> BSHIFT], 1u);
                r[4*k+1] = (unsigned short)atomicAdd(&cnt[vd[k].y >> BSHIFT], 1u);
                r[4*k+2] = (unsigned short)atomicAdd(&cnt[vd[k].z >> BSHIFT], 1u);
                r[4*k+3] = (unsigned short)atomicAdd(&cnt[vd[k].w >> BSHIFT], 1u);
            }
        }
        __syncthreads();
        // wave0: exclusive scan of cnt -> lbase; reserve global bases
        if (tid < 64) {
            unsigned run = 0;
            for (int c0 = 0; c0 < 256; c0 += 64) {
                unsigned v = cnt[c0 + tid];
                unsigned s = v;
                #pragma unroll
                for (int off = 1; off < 64; off <<= 1) {
                    unsigned o = __shfl_up(s, off);
                    if (tid >= off) s += o;
                }
                lbase[c0 + tid] = run + s - v;
                run += __shfl(s, 63);
            }
            if (tid == 0) s_tot = run;
        }
        if (tid < NBUK && cnt[tid])
            sbase[tid] = atomicAdd(&cursor[g * 256 + tid], cnt[tid]);
        __syncthreads();

        #pragma unroll
        for (int k = 0; k < 4; ++k) {
            if (vd[k].x >= 0) {
                int d0 = vd[k].x, d1 = vd[k].y, d2 = vd[k].z, d3 = vd[k].w;
                unsigned b0 = (unsigned)d0 >> BSHIFT, b1 = (unsigned)d1 >> BSHIFT;
                unsigned b2 = (unsigned)d2 >> BSHIFT, b3 = (unsigned)d3 >> BSHIFT;
                unsigned p0 = lbase[b0] + r[4*k+0];
                unsigned p1 = lbase[b1] + r[4*k+1];
                unsigned p2 = lbase[b2] + r[4*k+2];
                unsigned p3 = lbase[b3] + r[4*k+3];
                staged[p0] = ((unsigned)(d0 & (BSIZE-1)) << 20) | (unsigned)vs[k].x;
                staged[p1] = ((unsigned)(d1 & (BSIZE-1)) << 20) | (unsigned)vs[k].y;
                staged[p2] = ((unsigned)(d2 & (BSIZE-1)) << 20) | (unsigned)vs[k].z;
                staged[p3] = ((unsigned)(d3 & (BSIZE-1)) << 20) | (unsigned)vs[k].w;
                sbuck[p0] = (unsigned char)b0;
                sbuck[p1] = (unsigned char)b1;
                sbuck[p2] = (unsigned char)b2;
                sbuck[p3] = (unsigned char)b3;
            }
        }
        __syncthreads();
        unsigned tot = s_tot;
        for (unsigned pos = tid; pos < tot; pos += 256) {
            unsigned b = sbuck[pos];
            unsigned gp = sbase[b] + (pos - lbase[b]);
            if (gp < (unsigned)capG)
                slab[((size_t)g * NBUK + b) * capG + gp] = staged[pos];
        }
        __syncthreads();
    }
    if (blockIdx.x == 0 && tid < (E & 3)) {
        int i = (E & ~3) + tid;
        int d = dst[i];
        unsigned b = (unsigned)d >> BSHIFT;
        unsigned p = atomicAdd(&cursor[b], 1u);
        if (p < (unsigned)capG)
            slab[(size_t)b * capG + p] =
                ((unsigned)(d & (BSIZE-1)) << 20) | (unsigned)src[i];
    }
}

// ===== K2 (fused): hist role (blocks < 2*NBUK) || h=x@W role (rest) =========
// 16KB LDS -> 10 blocks/CU; h-role saturates HBM while hist hides its latency.
__global__ void __launch_bounds__(FNT)
hist_h_kernel(const unsigned* __restrict__ slab, int capG,
              const unsigned* __restrict__ cursor,
              unsigned* __restrict__ deg0, unsigned* __restrict__ deg1,
              const float* __restrict__ x, const float* __restrict__ W,
              float* __restrict__ h, int N, int NBUK, int nhblocks) {
    __shared__ unsigned hist[BSIZE];   // 16 KB
    int bp = blockIdx.x, tid = threadIdx.x;

    if (bp < 2 * NBUK) {
        // ---------------- hist role: 8-segment MLP, half-bucket -------------
        int b = bp >> 1, half = bp & 1;
        for (int t = tid; t < BSIZE; t += FNT) hist[t] = 0;
        __syncthreads();
        int g0 = half * 16;
        for (int gg = g0; gg < g0 + 16; gg += 8) {
            unsigned n[8], maxn = 0;
            const unsigned* sp[8];
            #pragma unroll
            for (int k = 0; k < 8; ++k) {
                unsigned nn = cursor[(gg + k) * 256 + b];
                if (nn > (unsigned)capG) nn = capG;
                n[k] = nn; if (nn > maxn) maxn = nn;
                sp[k] = slab + ((size_t)(gg + k) * NBUK + b) * capG;
            }
            for (unsigned i = tid; i < maxn; i += FNT) {
                unsigned e[8];
                #pragma unroll
                for (int k = 0; k < 8; ++k) e[k] = (i < n[k]) ? sp[k][i] : 0xFFFFFFFFu;
                #pragma unroll
                for (int k = 0; k < 8; ++k)
                    if (e[k] != 0xFFFFFFFFu) atomicAdd(&hist[e[k] >> 20], 1u);
            }
        }
        __syncthreads();
        int base = b << BSHIFT;
        int lim = N - base; if (lim > BSIZE) lim = BSIZE;
        unsigned* degP = half ? deg1 : deg0;
        for (int t = tid; t < lim; t += FNT) degP[base + t] = hist[t];
    } else {
        // ---------------- h role: grid-stride h[node] = dot(x[node,:],W) ----
        int hb = bp - 2 * NBUK;
        int gwave = (hb * FNT + tid) >> 6;
        int lane = tid & 63;
        int half = lane >> 5;
        int l32  = lane & 31;
        int total_waves = (nhblocks * FNT) >> 6;
        float4 wv = ((const float4*)W)[l32];
        for (int node = gwave * 2 + half; node < N; node += total_waves * 2) {
            float4 xv = ((const float4*)(x + (size_t)node * 128))[l32];
            float v = xv.x * wv.x + xv.y * wv.y + xv.z * wv.z + xv.w * wv.w;
            #pragma unroll
            for (int d = 16; d >= 1; d >>= 1) v += __shfl_xor(v, d);
            if (l32 == 0) h[node] = v;
        }
    }
}

// ===== K3: finalize: dinv -> hsh, pkw (streaming, tiny) =====================
__global__ void finalize_kernel(const float* __restrict__ h,
                                const unsigned* __restrict__ deg0,
                                const unsigned* __restrict__ deg1,
                                const int* __restrict__ batch,
                                unsigned short* __restrict__ hsh,
                                unsigned* __restrict__ pkw, int N) {
    int i = blockIdx.x * blockDim.x + threadIdx.x;
    int stride = gridDim.x * blockDim.x;
    for (; i < N; i += stride) {
        float di = rsqrtf((float)(deg0[i] + deg1[i] + 1u));
        hsh[i] = __half_as_ushort(__float2half(di * h[i]));
        pkw[i] = ((unsigned)batch[i] << 16) | __half_as_ushort(__float2half(di));
    }
}

// ===== K4: aggregate — 4 quarter-blocks/bucket, 8-segment MLP, window pool ==
__global__ void __launch_bounds__(512)
aggregate_kernel(const unsigned* __restrict__ slab, int capG,
                 const unsigned* __restrict__ cursor,
                 const unsigned* __restrict__ pkw,
                 const unsigned short* __restrict__ hsh,
                 float* __restrict__ pooled, int N, int NBUK) {
    __shared__ unsigned pkw_s[BSIZE];        // 16 KB
    __shared__ float win[REPL * WPAD];       // 8.2 KB
    int bp = blockIdx.x, tid = threadIdx.x;
    int b = bp >> 2, q = bp & 3;
    int base = b << BSHIFT;
    int lim = N - base; if (lim > BSIZE) lim = BSIZE;

    for (int t = tid; t < BSIZE; t += 512) pkw_s[t] = (t < lim) ? pkw[base + t] : 0u;
    for (int t = tid; t < REPL * WPAD; t += 512) win[t] = 0.0f;
    __syncthreads();
    int g_lo = (int)(pkw_s[0] >> 16);
    int g_hi = (lim > 0) ? (int)(pkw_s[lim - 1] >> 16) : g_lo;
    int width = g_hi - g_lo + 1;
    bool windowed = (width <= WINDOW);
    int r = tid & (REPL - 1);

    int n0 = q * (BSIZE / 4);
    int n1 = (q + 1) * (BSIZE / 4); if (n1 > lim) n1 = lim;
    for (int t = n0 + tid; t < n1; t += 512) {
        unsigned w = pkw_s[t];
        float di = __half2float(__ushort_as_half((unsigned short)(w & 0xFFFFu)));
        float c = di * __half2float(__ushort_as_half(hsh[base + t]));
        if (windowed) atomicAdd(&win[r * WPAD + ((w >> 16) - g_lo)], c);
        else          atomicAdd(&pooled[w >> 16], c);
    }

    int g0 = q * 8;
    unsigned n[8], maxn = 0;
    const unsigned* sp[8];
    #pragma unroll
    for (int k = 0; k < 8; ++k) {
        unsigned nn = cursor[(g0 + k) * 256 + b];
        if (nn > (unsigned)capG) nn = capG;
        n[k] = nn; if (nn > maxn) maxn = nn;
        sp[k] = slab + ((size_t)(g0 + k) * NBUK + b) * capG;
    }
    for (unsigned i = tid; i < maxn; i += 512) {
        unsigned e[8]; bool v[8];
        #pragma unroll
        for (int k = 0; k < 8; ++k) { v[k] = (i < n[k]); e[k] = v[k] ? sp[k][i] : 0u; }
        unsigned w[8];
        #pragma unroll
        for (int k = 0; k < 8; ++k) w[k] = pkw_s[e[k] >> 20];
        unsigned short hb[8];
        #pragma unroll
        for (int k = 0; k < 8; ++k) hb[k] = hsh[e[k] & 0xFFFFFu];
        #pragma unroll
        for (int k = 0; k < 8; ++k) {
            float hv = __half2float(__ushort_as_half(hb[k]));
            float di = __half2float(__ushort_as_half((unsigned short)(w[k] & 0xFFFFu)));
            float c = v[k] ? hv * di : 0.0f;
            if (windowed) atomicAdd(&win[r * WPAD + ((w[k] >> 16) - g_lo)], c);
            else if (v[k]) atomicAdd(&pooled[w[k] >> 16], c);
        }
    }
    __syncthreads();
    if (windowed) {
        for (int g = tid; g < width; g += 512) {
            float s = 0.0f;
            #pragma unroll
            for (int rr = 0; rr < REPL; ++rr) s += win[rr * WPAD + g];
            atomicAdd(&pooled[g_lo + g], s);
        }
    }
}

// ===== K5: affine ==========================================================
__global__ void out_kernel(const float* __restrict__ pooled,
                           const float* __restrict__ pp_w,
                           const float* __restrict__ pp_b,
                           float* __restrict__ out) {
    int g = blockIdx.x * blockDim.x + threadIdx.x;
    if (g < NUM_GRAPHS) out[g] = pooled[g] * pp_w[0] + pp_b[0];
}

// ===== Fallback path (tiny ws / oversized N): correctness only =============
__global__ void deg_atomic_kernel(const int* __restrict__ dst, int E,
                                  unsigned* __restrict__ deg) {
    int tid = blockIdx.x * blockDim.x + threadIdx.x;
    int stride = gridDim.x * blockDim.x;
    for (int i = tid; i < E; i += stride) atomicAdd(&deg[dst[i]], 1u);
}

__global__ void node_fb_kernel(const float* __restrict__ x,
                               const float* __restrict__ W,
                               const unsigned* __restrict__ deg,
                               const int* __restrict__ batch,
                               unsigned short* __restrict__ hsh,
                               unsigned* __restrict__ pkw, int N) {
    int gtid = blockIdx.x * blockDim.x + threadIdx.x;
    int wave = gtid >> 6;
    int lane = threadIdx.x & 63;
    int half = lane >> 5;
    int l32  = lane & 31;
    int node = wave * 2 + half;
    if (node >= N) return;
    float4 xv = ((const float4*)(x + (size_t)node * 128))[l32];
    float4 wv = ((const float4*)W)[l32];
    float v = xv.x * wv.x + xv.y * wv.y + xv.z * wv.z + xv.w * wv.w;
    #pragma unroll
    for (int d = 16; d >= 1; d >>= 1) v += __shfl_xor(v, d);
    if (l32 == 0) {
        float di = rsqrtf((float)(deg[node] + 1u));
        hsh[node] = __half_as_ushort(__float2half(di * v));
        pkw[node] = ((unsigned)batch[node] << 16) | __half_as_ushort(__float2half(di));
    }
}

__global__ void pool_self_fb_kernel(const unsigned short* __restrict__ hsh,
                                    const unsigned* __restrict__ pkw,
                                    float* __restrict__ pooled, int N) {
    int i = blockIdx.x * blockDim.x + threadIdx.x;
    if (i >= N) return;
    unsigned w = pkw[i];
    float di = __half2float(__ushort_as_half((unsigned short)(w & 0xFFFFu)));
    atomicAdd(&pooled[w >> 16], di * __half2float(__ushort_as_half(hsh[i])));
}

__global__ void __launch_bounds__(512)
edge_direct_kernel(const int* __restrict__ src, const int* __restrict__ dst, int E,
                   const unsigned short* __restrict__ hsh,
                   const unsigned* __restrict__ pkw,
                   float* __restrict__ pooled) {
    __shared__ float pool[NUM_GRAPHS];
    for (int g = threadIdx.x; g < NUM_GRAPHS; g += 512) pool[g] = 0.0f;
    __syncthreads();
    int tid = blockIdx.x * 512 + threadIdx.x;
    int stride = gridDim.x * 512;
    for (int i = tid; i < E; i += stride) {
        unsigned w = pkw[dst[i]];
        float c = __half2float(__ushort_as_half(hsh[src[i]])) *
                  __half2float(__ushort_as_half((unsigned short)(w & 0xFFFFu)));
        atomicAdd(&pool[w >> 16], c);
    }
    __syncthreads();
    for (int g = threadIdx.x; g < NUM_GRAPHS; g += 512)
        if (pool[g] != 0.0f) atomicAdd(&pooled[g], pool[g]);
}

extern "C" void kernel_launch(void* const* d_in, const int* in_sizes, int n_in,
                              void* d_out, int out_size, void* d_ws, size_t ws_size,
                              hipStream_t stream) {
    const float* x    = (const float*)d_in[0];
    const float* W    = (const float*)d_in[1];
    const float* pp_w = (const float*)d_in[2];
    const float* pp_b = (const float*)d_in[3];
    const int*   ei   = (const int*)d_in[4];
    const int*   batch= (const int*)d_in[5];
    float* out = (float*)d_out;

    const int E = in_sizes[4] / 2;
    const int N = in_sizes[5];
    const int* src = ei;
    const int* dst = ei + E;
    int NBUK = (N + BSIZE - 1) >> BSHIFT;
    int nchunks = (E + CHUNK - 1) / CHUNK;

    char* ws = (char*)d_ws;
    size_t off = 0;
    auto alloc = [&](size_t bytes) {
        size_t o = off; off = (off + bytes + 255) & ~(size_t)255; return o;
    };
    size_t zero_bytes = (size_t)NUM_GRAPHS * 4 + (size_t)NGRP * 256 * 4;
    size_t zero_off   = alloc(zero_bytes);
    float*    pooled = (float*)(ws + zero_off);
    unsigned* cursor = (unsigned*)(ws + zero_off + (size_t)NUM_GRAPHS * 4);

    size_t h_off    = alloc((size_t)N * 4);
    size_t deg0_off = alloc((size_t)N * 4);      // also fallback deg
    size_t deg1_off = alloc((size_t)N * 4);
    size_t hsh_off  = alloc((size_t)N * 2);
    size_t pkw_off  = alloc((size_t)N * 4);

    int meanG = E / (NBUK * NGRP) + 1;
    int capG = (meanG + meanG / 8 + 512 + 3) & ~3;   // ~17 sigma, 16B-aligned
    size_t slab_off = alloc((size_t)NGRP * NBUK * (size_t)capG * 4);

    bool fast_ok = (NBUK <= 256) && (N <= (1 << 20)) && (off <= ws_size);

    float*          h    = (float*)(ws + h_off);
    unsigned*       deg0 = (unsigned*)(ws + deg0_off);
    unsigned*       deg1 = (unsigned*)(ws + deg1_off);
    unsigned short* hsh  = (unsigned short*)(ws + hsh_off);
    unsigned*       pkw  = (unsigned*)(ws + pkw_off);
    unsigned*       slab = (unsigned*)(ws + slab_off);

    hipMemsetAsync(ws + zero_off, 0, zero_bytes, stream);

    if (fast_ok) {
        int grid = nchunks < 4096 ? nchunks : 4096;
        pair_scatter_kernel<<<grid, 256, 0, stream>>>(src, dst, E, nchunks, NBUK,
                                                      capG, cursor, slab);
        int nhblocks = 2048;   // h-role blocks
        hist_h_kernel<<<2 * NBUK + nhblocks, FNT, 0, stream>>>(
            slab, capG, cursor, deg0, deg1, x, W, h, N, NBUK, nhblocks);
        finalize_kernel<<<1024, 256, 0, stream>>>(h, deg0, deg1, batch, hsh, pkw, N);
        aggregate_kernel<<<4 * NBUK, 512, 0, stream>>>(slab, capG, cursor, pkw,
                                                       hsh, pooled, N, NBUK);
    } else {
        hipMemsetAsync(deg0, 0, (size_t)N * 4, stream);
        deg_atomic_kernel<<<2048, 256, 0, stream>>>(dst, E, deg0);
        int node_blocks = (N + 7) / 8;
        node_fb_kernel<<<node_blocks, 256, 0, stream>>>(x, W, deg0, batch, hsh, pkw, N);
        pool_self_fb_kernel<<<(N + 255) / 256, 256, 0, stream>>>(hsh, pkw, pooled, N);
        edge_direct_kernel<<<512, 512, 0, stream>>>(src, dst, E, hsh, pkw, pooled);
    }

    out_kernel<<<(NUM_GRAPHS + 255) / 256, 256, 0, stream>>>(pooled, pp_w, pp_b, out);
}

// Round 17
// 270.870 us; speedup vs baseline: 4.4804x; 1.0198x over previous
//
#include <hip/hip_runtime.h>
#include <hip/hip_fp16.h>

#define NUM_GRAPHS 8192
#define BSHIFT 12
#define BSIZE 4096     // nodes per bucket
#define CHUNK 4096     // edges per chunk
#define NGRP 32        // cursor/slab groups
#define REPL 8         // aggregate window replicas
#define WINDOW 256     // max graphs spanned per bucket
#define WPAD 257       // padded replica stride
#define FNT 512        // hist_h block size
#define SGRID 2048     // scatter-role blocks in dispatch 1
#define HGRID1 2048    // h-role blocks in dispatch 1

// ===== K1 (fused): scatter into sub-slabs ∥ h = x@W over [0, Nh) ===========
// Roles interleaved by bid&1; scatter LDS 21.2KB -> ~7 blocks/CU mixed.
__global__ void __launch_bounds__(256)
scatter_h_kernel(const int* __restrict__ src, const int* __restrict__ dst,
                 int E, int nchunks, int NBUK, int capG,
                 unsigned* __restrict__ cursor, unsigned* __restrict__ slab,
                 const float* __restrict__ x, const float* __restrict__ W,
                 float* __restrict__ h, int Nh) {
    __shared__ unsigned cnt[256];
    __shared__ unsigned lbase[256];
    __shared__ unsigned sbase[256];
    __shared__ unsigned staged[CHUNK];
    __shared__ unsigned char sbuck[CHUNK];
    __shared__ unsigned s_tot;

    int bid = blockIdx.x;
    int tid = threadIdx.x;

    if ((bid & 1) == 0) {
        // ---------------- scatter role: sid in [0, SGRID) -------------------
        int sid = bid >> 1;
        const int4* s4 = (const int4*)src;
        const int4* d4 = (const int4*)dst;
        int E4 = E >> 2;
        int g = sid & (NGRP - 1);

        for (int chunk = sid; chunk < nchunks; chunk += SGRID) {
            cnt[tid] = 0; __syncthreads();
            int b4 = chunk * (CHUNK / 4);
            int4 vd[4], vs[4];
            unsigned short r[16];
            #pragma unroll
            for (int k = 0; k < 4; ++k) {
                int idx = b4 + k * 256 + tid;
                if (idx < E4) { vd[k] = d4[idx]; vs[k] = s4[idx]; }
                else          { vd[k] = make_int4(-1, -1, -1, -1); }
            }
            #pragma unroll
            for (int k = 0; k < 4; ++k) {
                if (vd[k].x >= 0) {
                    r[4*k+0] = (unsigned short)atomicAdd(&cnt[vd[k].x >> BSHIFT], 1u);
                    r[4*k+1] = (unsigned short)atomicAdd(&cnt[vd[k].y >> BSHIFT], 1u);
                    r[4*k+2] = (unsigned short)atomicAdd(&cnt[vd[k].z >> BSHIFT], 1u);
                    r[4*k+3] = (unsigned short)atomicAdd(&cnt[vd[k].w >> BSHIFT], 1u);
                }
            }
            __syncthreads();
            // wave0: exclusive scan of cnt -> lbase
            if (tid < 64) {
                unsigned run = 0;
                for (int c0 = 0; c0 < 256; c0 += 64) {
                    unsigned v = cnt[c0 + tid];
                    unsigned s = v;
                    #pragma unroll
                    for (int off = 1; off < 64; off <<= 1) {
                        unsigned o = __shfl_up(s, off);
                        if (tid >= off) s += o;
                    }
                    lbase[c0 + tid] = run + s - v;
                    run += __shfl(s, 63);
                }
                if (tid == 0) s_tot = run;
            }
            if (tid < NBUK && cnt[tid])
                sbase[tid] = atomicAdd(&cursor[g * 256 + tid], cnt[tid]);
            __syncthreads();

            #pragma unroll
            for (int k = 0; k < 4; ++k) {
                if (vd[k].x >= 0) {
                    int d0 = vd[k].x, d1 = vd[k].y, d2 = vd[k].z, d3 = vd[k].w;
                    unsigned b0 = (unsigned)d0 >> BSHIFT, b1 = (unsigned)d1 >> BSHIFT;
                    unsigned b2 = (unsigned)d2 >> BSHIFT, b3 = (unsigned)d3 >> BSHIFT;
                    unsigned p0 = lbase[b0] + r[4*k+0];
                    unsigned p1 = lbase[b1] + r[4*k+1];
                    unsigned p2 = lbase[b2] + r[4*k+2];
                    unsigned p3 = lbase[b3] + r[4*k+3];
                    staged[p0] = ((unsigned)(d0 & (BSIZE-1)) << 20) | (unsigned)vs[k].x;
                    staged[p1] = ((unsigned)(d1 & (BSIZE-1)) << 20) | (unsigned)vs[k].y;
                    staged[p2] = ((unsigned)(d2 & (BSIZE-1)) << 20) | (unsigned)vs[k].z;
                    staged[p3] = ((unsigned)(d3 & (BSIZE-1)) << 20) | (unsigned)vs[k].w;
                    sbuck[p0] = (unsigned char)b0;
                    sbuck[p1] = (unsigned char)b1;
                    sbuck[p2] = (unsigned char)b2;
                    sbuck[p3] = (unsigned char)b3;
                }
            }
            __syncthreads();
            unsigned tot = s_tot;
            for (unsigned pos = tid; pos < tot; pos += 256) {
                unsigned b = sbuck[pos];
                unsigned gp = sbase[b] + (pos - lbase[b]);
                if (gp < (unsigned)capG)
                    slab[((size_t)g * NBUK + b) * capG + gp] = staged[pos];
            }
            __syncthreads();
        }
        if (sid == 0 && tid < (E & 3)) {
            int i = (E & ~3) + tid;
            int d = dst[i];
            unsigned b = (unsigned)d >> BSHIFT;
            unsigned p = atomicAdd(&cursor[b], 1u);
            if (p < (unsigned)capG)
                slab[(size_t)b * capG + p] =
                    ((unsigned)(d & (BSIZE-1)) << 20) | (unsigned)src[i];
        }
    } else {
        // ---------------- h role: nodes [0, Nh) -----------------------------
        int hid = bid >> 1;
        int gwave = (hid * 256 + tid) >> 6;
        int lane = tid & 63;
        int half = lane >> 5;
        int l32  = lane & 31;
        int total_waves = (HGRID1 * 256) >> 6;
        float4 wv = ((const float4*)W)[l32];
        for (int node = gwave * 2 + half; node < Nh; node += total_waves * 2) {
            float4 xv = ((const float4*)(x + (size_t)node * 128))[l32];
            float v = xv.x * wv.x + xv.y * wv.y + xv.z * wv.z + xv.w * wv.w;
            #pragma unroll
            for (int d = 16; d >= 1; d >>= 1) v += __shfl_xor(v, d);
            if (l32 == 0) h[node] = v;
        }
    }
}

// ===== K2 (fused): hist role (blocks < 2*NBUK) ∥ h over [Nh, N) =============
__global__ void __launch_bounds__(FNT)
hist_h_kernel(const unsigned* __restrict__ slab, int capG,
              const unsigned* __restrict__ cursor,
              unsigned* __restrict__ deg0, unsigned* __restrict__ deg1,
              const float* __restrict__ x, const float* __restrict__ W,
              float* __restrict__ h, int Nh, int N, int NBUK, int nhblocks) {
    __shared__ unsigned hist[BSIZE];   // 16 KB
    int bp = blockIdx.x, tid = threadIdx.x;

    if (bp < 2 * NBUK) {
        int b = bp >> 1, half = bp & 1;
        for (int t = tid; t < BSIZE; t += FNT) hist[t] = 0;
        __syncthreads();
        int g0 = half * 16;
        for (int gg = g0; gg < g0 + 16; gg += 8) {
            unsigned n[8], maxn = 0;
            const unsigned* sp[8];
            #pragma unroll
            for (int k = 0; k < 8; ++k) {
                unsigned nn = cursor[(gg + k) * 256 + b];
                if (nn > (unsigned)capG) nn = capG;
                n[k] = nn; if (nn > maxn) maxn = nn;
                sp[k] = slab + ((size_t)(gg + k) * NBUK + b) * capG;
            }
            for (unsigned i = tid; i < maxn; i += FNT) {
                unsigned e[8];
                #pragma unroll
                for (int k = 0; k < 8; ++k) e[k] = (i < n[k]) ? sp[k][i] : 0xFFFFFFFFu;
                #pragma unroll
                for (int k = 0; k < 8; ++k)
                    if (e[k] != 0xFFFFFFFFu) atomicAdd(&hist[e[k] >> 20], 1u);
            }
        }
        __syncthreads();
        int base = b << BSHIFT;
        int lim = N - base; if (lim > BSIZE) lim = BSIZE;
        unsigned* degP = half ? deg1 : deg0;
        for (int t = tid; t < lim; t += FNT) degP[base + t] = hist[t];
    } else {
        int hb = bp - 2 * NBUK;
        int gwave = (hb * FNT + tid) >> 6;
        int lane = tid & 63;
        int half = lane >> 5;
        int l32  = lane & 31;
        int total_waves = (nhblocks * FNT) >> 6;
        float4 wv = ((const float4*)W)[l32];
        for (int node = Nh + gwave * 2 + half; node < N; node += total_waves * 2) {
            float4 xv = ((const float4*)(x + (size_t)node * 128))[l32];
            float v = xv.x * wv.x + xv.y * wv.y + xv.z * wv.z + xv.w * wv.w;
            #pragma unroll
            for (int d = 16; d >= 1; d >>= 1) v += __shfl_xor(v, d);
            if (l32 == 0) h[node] = v;
        }
    }
}

// ===== K3: finalize: dinv -> hsh, pkw (streaming, tiny) =====================
__global__ void finalize_kernel(const float* __restrict__ h,
                                const unsigned* __restrict__ deg0,
                                const unsigned* __restrict__ deg1,
                                const int* __restrict__ batch,
                                unsigned short* __restrict__ hsh,
                                unsigned* __restrict__ pkw, int N) {
    int i = blockIdx.x * blockDim.x + threadIdx.x;
    int stride = gridDim.x * blockDim.x;
    for (; i < N; i += stride) {
        float di = rsqrtf((float)(deg0[i] + deg1[i] + 1u));
        hsh[i] = __half_as_ushort(__float2half(di * h[i]));
        pkw[i] = ((unsigned)batch[i] << 16) | __half_as_ushort(__float2half(di));
    }
}

// ===== K4: aggregate — 4 quarter-blocks/bucket, 8-segment MLP, window pool ==
__global__ void __launch_bounds__(512)
aggregate_kernel(const unsigned* __restrict__ slab, int capG,
                 const unsigned* __restrict__ cursor,
                 const unsigned* __restrict__ pkw,
                 const unsigned short* __restrict__ hsh,
                 float* __restrict__ pooled, int N, int NBUK) {
    __shared__ unsigned pkw_s[BSIZE];        // 16 KB
    __shared__ float win[REPL * WPAD];       // 8.2 KB
    int bp = blockIdx.x, tid = threadIdx.x;
    int b = bp >> 2, q = bp & 3;
    int base = b << BSHIFT;
    int lim = N - base; if (lim > BSIZE) lim = BSIZE;

    for (int t = tid; t < BSIZE; t += 512) pkw_s[t] = (t < lim) ? pkw[base + t] : 0u;
    for (int t = tid; t < REPL * WPAD; t += 512) win[t] = 0.0f;
    __syncthreads();
    int g_lo = (int)(pkw_s[0] >> 16);
    int g_hi = (lim > 0) ? (int)(pkw_s[lim - 1] >> 16) : g_lo;
    int width = g_hi - g_lo + 1;
    bool windowed = (width <= WINDOW);
    int r = tid & (REPL - 1);

    int n0 = q * (BSIZE / 4);
    int n1 = (q + 1) * (BSIZE / 4); if (n1 > lim) n1 = lim;
    for (int t = n0 + tid; t < n1; t += 512) {
        unsigned w = pkw_s[t];
        float di = __half2float(__ushort_as_half((unsigned short)(w & 0xFFFFu)));
        float c = di * __half2float(__ushort_as_half(hsh[base + t]));
        if (windowed) atomicAdd(&win[r * WPAD + ((w >> 16) - g_lo)], c);
        else          atomicAdd(&pooled[w >> 16], c);
    }

    int g0 = q * 8;
    unsigned n[8], maxn = 0;
    const unsigned* sp[8];
    #pragma unroll
    for (int k = 0; k < 8; ++k) {
        unsigned nn = cursor[(g0 + k) * 256 + b];
        if (nn > (unsigned)capG) nn = capG;
        n[k] = nn; if (nn > maxn) maxn = nn;
        sp[k] = slab + ((size_t)(g0 + k) * NBUK + b) * capG;
    }
    for (unsigned i = tid; i < maxn; i += 512) {
        unsigned e[8]; bool v[8];
        #pragma unroll
        for (int k = 0; k < 8; ++k) { v[k] = (i < n[k]); e[k] = v[k] ? sp[k][i] : 0u; }
        unsigned w[8];
        #pragma unroll
        for (int k = 0; k < 8; ++k) w[k] = pkw_s[e[k] >> 20];
        unsigned short hb[8];
        #pragma unroll
        for (int k = 0; k < 8; ++k) hb[k] = hsh[e[k] & 0xFFFFFu];
        #pragma unroll
        for (int k = 0; k < 8; ++k) {
            float hv = __half2float(__ushort_as_half(hb[k]));
            float di = __half2float(__ushort_as_half((unsigned short)(w[k] & 0xFFFFu)));
            float c = v[k] ? hv * di : 0.0f;
            if (windowed) atomicAdd(&win[r * WPAD + ((w[k] >> 16) - g_lo)], c);
            else if (v[k]) atomicAdd(&pooled[w[k] >> 16], c);
        }
    }
    __syncthreads();
    if (windowed) {
        for (int g = tid; g < width; g += 512) {
            float s = 0.0f;
            #pragma unroll
            for (int rr = 0; rr < REPL; ++rr) s += win[rr * WPAD + g];
            atomicAdd(&pooled[g_lo + g], s);
        }
    }
}

// ===== K5: affine ==========================================================
__global__ void out_kernel(const float* __restrict__ pooled,
                           const float* __restrict__ pp_w,
                           const float* __restrict__ pp_b,
                           float* __restrict__ out) {
    int g = blockIdx.x * blockDim.x + threadIdx.x;
    if (g < NUM_GRAPHS) out[g] = pooled[g] * pp_w[0] + pp_b[0];
}

// ===== Fallback path (tiny ws / oversized N): correctness only =============
__global__ void deg_atomic_kernel(const int* __restrict__ dst, int E,
                                  unsigned* __restrict__ deg) {
    int tid = blockIdx.x * blockDim.x + threadIdx.x;
    int stride = gridDim.x * blockDim.x;
    for (int i = tid; i < E; i += stride) atomicAdd(&deg[dst[i]], 1u);
}

__global__ void node_fb_kernel(const float* __restrict__ x,
                               const float* __restrict__ W,
                               const unsigned* __restrict__ deg,
                               const int* __restrict__ batch,
                               unsigned short* __restrict__ hsh,
                               unsigned* __restrict__ pkw, int N) {
    int gtid = blockIdx.x * blockDim.x + threadIdx.x;
    int wave = gtid >> 6;
    int lane = threadIdx.x & 63;
    int half = lane >> 5;
    int l32  = lane & 31;
    int node = wave * 2 + half;
    if (node >= N) return;
    float4 xv = ((const float4*)(x + (size_t)node * 128))[l32];
    float4 wv = ((const float4*)W)[l32];
    float v = xv.x * wv.x + xv.y * wv.y + xv.z * wv.z + xv.w * wv.w;
    #pragma unroll
    for (int d = 16; d >= 1; d >>= 1) v += __shfl_xor(v, d);
    if (l32 == 0) {
        float di = rsqrtf((float)(deg[node] + 1u));
        hsh[node] = __half_as_ushort(__float2half(di * v));
        pkw[node] = ((unsigned)batch[node] << 16) | __half_as_ushort(__float2half(di));
    }
}

__global__ void pool_self_fb_kernel(const unsigned short* __restrict__ hsh,
                                    const unsigned* __restrict__ pkw,
                                    float* __restrict__ pooled, int N) {
    int i = blockIdx.x * blockDim.x + threadIdx.x;
    if (i >= N) return;
    unsigned w = pkw[i];
    float di = __half2float(__ushort_as_half((unsigned short)(w & 0xFFFFu)));
    atomicAdd(&pooled[w >> 16], di * __half2float(__ushort_as_half(hsh[i])));
}

__global__ void __launch_bounds__(512)
edge_direct_kernel(const int* __restrict__ src, const int* __restrict__ dst, int E,
                   const unsigned short* __restrict__ hsh,
                   const unsigned* __restrict__ pkw,
                   float* __restrict__ pooled) {
    __shared__ float pool[NUM_GRAPHS];
    for (int g = threadIdx.x; g < NUM_GRAPHS; g += 512) pool[g] = 0.0f;
    __syncthreads();
    int tid = blockIdx.x * 512 + threadIdx.x;
    int stride = gridDim.x * 512;
    for (int i = tid; i < E; i += stride) {
        unsigned w = pkw[dst[i]];
        float c = __half2float(__ushort_as_half(hsh[src[i]])) *
                  __half2float(__ushort_as_half((unsigned short)(w & 0xFFFFu)));
        atomicAdd(&pool[w >> 16], c);
    }
    __syncthreads();
    for (int g = threadIdx.x; g < NUM_GRAPHS; g += 512)
        if (pool[g] != 0.0f) atomicAdd(&pooled[g], pool[g]);
}

extern "C" void kernel_launch(void* const* d_in, const int* in_sizes, int n_in,
                              void* d_out, int out_size, void* d_ws, size_t ws_size,
                              hipStream_t stream) {
    const float* x    = (const float*)d_in[0];
    const float* W    = (const float*)d_in[1];
    const float* pp_w = (const float*)d_in[2];
    const float* pp_b = (const float*)d_in[3];
    const int*   ei   = (const int*)d_in[4];
    const int*   batch= (const int*)d_in[5];
    float* out = (float*)d_out;

    const int E = in_sizes[4] / 2;
    const int N = in_sizes[5];
    const int* src = ei;
    const int* dst = ei + E;
    int NBUK = (N + BSIZE - 1) >> BSHIFT;
    int nchunks = (E + CHUNK - 1) / CHUNK;

    char* ws = (char*)d_ws;
    size_t off = 0;
    auto alloc = [&](size_t bytes) {
        size_t o = off; off = (off + bytes + 255) & ~(size_t)255; return o;
    };
    size_t zero_bytes = (size_t)NUM_GRAPHS * 4 + (size_t)NGRP * 256 * 4;
    size_t zero_off   = alloc(zero_bytes);
    float*    pooled = (float*)(ws + zero_off);
    unsigned* cursor = (unsigned*)(ws + zero_off + (size_t)NUM_GRAPHS * 4);

    size_t h_off    = alloc((size_t)N * 4);
    size_t deg0_off = alloc((size_t)N * 4);      // also fallback deg
    size_t deg1_off = alloc((size_t)N * 4);
    size_t hsh_off  = alloc((size_t)N * 2);
    size_t pkw_off  = alloc((size_t)N * 4);

    int meanG = E / (NBUK * NGRP) + 1;
    int capG = (meanG + meanG / 8 + 512 + 3) & ~3;   // ~17 sigma, 16B-aligned
    size_t slab_off = alloc((size_t)NGRP * NBUK * (size_t)capG * 4);

    bool fast_ok = (NBUK <= 256) && (N <= (1 << 20)) && (off <= ws_size);

    float*          h    = (float*)(ws + h_off);
    unsigned*       deg0 = (unsigned*)(ws + deg0_off);
    unsigned*       deg1 = (unsigned*)(ws + deg1_off);
    unsigned short* hsh  = (unsigned short*)(ws + hsh_off);
    unsigned*       pkw  = (unsigned*)(ws + pkw_off);
    unsigned*       slab = (unsigned*)(ws + slab_off);

    hipMemsetAsync(ws + zero_off, 0, zero_bytes, stream);

    if (fast_ok) {
        int Nh = N >> 1;
        scatter_h_kernel<<<SGRID + HGRID1, 256, 0, stream>>>(
            src, dst, E, nchunks, NBUK, capG, cursor, slab, x, W, h, Nh);
        int nhblocks = 2048;   // h-role blocks in dispatch 2
        hist_h_kernel<<<2 * NBUK + nhblocks, FNT, 0, stream>>>(
            slab, capG, cursor, deg0, deg1, x, W, h, Nh, N, NBUK, nhblocks);
        finalize_kernel<<<1024, 256, 0, stream>>>(h, deg0, deg1, batch, hsh, pkw, N);
        aggregate_kernel<<<4 * NBUK, 512, 0, stream>>>(slab, capG, cursor, pkw,
                                                       hsh, pooled, N, NBUK);
    } else {
        hipMemsetAsync(deg0, 0, (size_t)N * 4, stream);
        deg_atomic_kernel<<<2048, 256, 0, stream>>>(dst, E, deg0);
        int node_blocks = (N + 7) / 8;
        node_fb_kernel<<<node_blocks, 256, 0, stream>>>(x, W, deg0, batch, hsh, pkw, N);
        pool_self_fb_kernel<<<(N + 255) / 256, 256, 0, stream>>>(hsh, pkw, pooled, N);
        edge_direct_kernel<<<512, 512, 0, stream>>>(src, dst, E, hsh, pkw, pooled);
    }

    out_kernel<<<(NUM_GRAPHS + 255) / 256, 256, 0, stream>>>(pooled, pp_w, pp_b, out);
}